// Round 2
// baseline (1232.146 us; speedup 1.0000x reference)
//
#include <hip/hip_runtime.h>

typedef __attribute__((ext_vector_type(8))) short short8;
typedef __attribute__((ext_vector_type(4))) float floatx4;
typedef unsigned int uint32;

__device__ inline float b2f(unsigned short u) {
    union { uint32 i; float f; } x; x.i = ((uint32)u) << 16; return x.f;
}
__device__ inline float bl(uint32 v) {
    union { uint32 i; float f; } x; x.i = v << 16; return x.f;
}
__device__ inline float bh(uint32 v) {
    union { uint32 i; float f; } x; x.i = v & 0xffff0000u; return x.f;
}
__device__ inline unsigned short f2b(float f) {
    union { float f; uint32 u; } x; x.f = f;
    uint32 r = x.u + 0x7fffu + ((x.u >> 16) & 1u);
    return (unsigned short)(r >> 16);
}

// ---------------- CSR build ----------------

__global__ __launch_bounds__(256) void hist_k(const int* __restrict__ eidx,
                                              int* __restrict__ cnt, int E) {
    int e = blockIdx.x * 256 + threadIdx.x;
    if (e < E) atomicAdd(&cnt[eidx[E + e]], 1);
}

__global__ __launch_bounds__(256) void dinv_k(const int* __restrict__ cnt,
                                              float* __restrict__ dinv, int N) {
    int i = blockIdx.x * 256 + threadIdx.x;
    if (i < N) dinv[i] = rsqrtf((float)cnt[i] + 2.0f);
}

__global__ __launch_bounds__(256) void scanA_k(const int* __restrict__ cnt,
                                               int* __restrict__ bsum, int N) {
    __shared__ int s[256];
    int t = threadIdx.x, i = blockIdx.x * 256 + t;
    s[t] = (i < N) ? cnt[i] : 0;
    __syncthreads();
    for (int off = 128; off > 0; off >>= 1) {
        if (t < off) s[t] += s[t + off];
        __syncthreads();
    }
    if (t == 0) bsum[blockIdx.x] = s[0];
}

__global__ __launch_bounds__(512) void scanB_k(const int* __restrict__ bsum,
                                               int* __restrict__ boff, int nb) {
    __shared__ int s[512];
    int t = threadIdx.x;
    int v = (t < nb) ? bsum[t] : 0;
    s[t] = v;
    __syncthreads();
    for (int off = 1; off < 512; off <<= 1) {
        int x = (t >= off) ? s[t - off] : 0;
        __syncthreads();
        s[t] += x;
        __syncthreads();
    }
    if (t < nb) boff[t] = s[t] - v;  // exclusive
}

__global__ __launch_bounds__(256) void scanC_k(int* __restrict__ cnt,
                                               const int* __restrict__ boff,
                                               int* __restrict__ rowp, int N, int E) {
    __shared__ int s[256];
    int t = threadIdx.x, i = blockIdx.x * 256 + t;
    int v = (i < N) ? cnt[i] : 0;
    s[t] = v;
    __syncthreads();
    for (int off = 1; off < 256; off <<= 1) {
        int x = (t >= off) ? s[t - off] : 0;
        __syncthreads();
        s[t] += x;
        __syncthreads();
    }
    int start = boff[blockIdx.x] + s[t] - v;
    if (i < N) { rowp[i] = start; cnt[i] = start; }  // cnt becomes fill cursor
    if (i == N - 1) rowp[N] = E;
}

__global__ __launch_bounds__(256) void fill_k(const int* __restrict__ eidx,
                                              int* __restrict__ cursor,
                                              int* __restrict__ csr, int E) {
    int e = blockIdx.x * 256 + threadIdx.x;
    if (e < E) {
        int d = eidx[E + e];
        int p = atomicAdd(&cursor[d], 1);
        csr[p] = eidx[e];
    }
}

// ---------------- weight prep: W fp32 [128][128] -> Wt_hi/Wt_lo bf16 (transposed) ----

__global__ __launch_bounds__(256) void prep_w_k(const float* __restrict__ W,
                                                unsigned short* __restrict__ Wt_hi,
                                                unsigned short* __restrict__ Wt_lo) {
    int t = blockIdx.x * 256 + threadIdx.x;  // 64 blocks
    int c = t & 127, k = t >> 7;
    float w = W[k * 128 + c];
    unsigned short hi = f2b(w);
    float lo = w - b2f(hi);
    Wt_hi[c * 128 + k] = hi;
    Wt_lo[c * 128 + k] = f2b(lo);
}

// ---------------- GEMM (128-wide, MFMA 16x16x32 bf16, split-W for fp32 accuracy) ----
// ASRC 0: A is fp32 (convert to bf16 in-flight)    ASRC 1: A is bf16 storage
// MODE 0: out = dinv[i] * (A @ W)   (z for conv)   MODE 1: out = tanh(A @ W + bias)

template <int ASRC, int MODE>
__global__ __launch_bounds__(256) void gemm128_k(
    const void* __restrict__ Asrc,
    const unsigned short* __restrict__ Wt_hi,
    const unsigned short* __restrict__ Wt_lo,
    const float* __restrict__ dinv, const float* __restrict__ bias,
    unsigned short* __restrict__ out, int N) {
    int tid = threadIdx.x;
    int wave = tid >> 6, lane = tid & 63;
    int quad = lane >> 4, r = lane & 15;
    int m_base = blockIdx.x * 16;

    int rowA = m_base + r;
    if (rowA >= N) rowA = N - 1;  // clamp (stores guarded below)

    short8 afrag[4];
    if (ASRC == 0) {
        const float* Af = (const float*)Asrc;
#pragma unroll
        for (int kc = 0; kc < 4; ++kc) {
            const float* p = Af + (size_t)rowA * 128 + kc * 32 + quad * 8;
            short8 a;
#pragma unroll
            for (int j = 0; j < 8; ++j) a[j] = (short)f2b(p[j]);
            afrag[kc] = a;
        }
    } else {
        const short* Ap = (const short*)Asrc;
#pragma unroll
        for (int kc = 0; kc < 4; ++kc)
            afrag[kc] = *(const short8*)(Ap + (size_t)rowA * 128 + kc * 32 + quad * 8);
    }

    const short* Wh = (const short*)Wt_hi;
    const short* Wl = (const short*)Wt_lo;

#pragma unroll
    for (int ct = 0; ct < 2; ++ct) {
        int n = wave * 32 + ct * 16 + r;
        floatx4 acc = {0.f, 0.f, 0.f, 0.f};
#pragma unroll
        for (int kc = 0; kc < 4; ++kc) {
            short8 bh8 = *(const short8*)(Wh + n * 128 + kc * 32 + quad * 8);
            acc = __builtin_amdgcn_mfma_f32_16x16x32_bf16(afrag[kc], bh8, acc, 0, 0, 0);
            short8 bl8 = *(const short8*)(Wl + n * 128 + kc * 32 + quad * 8);
            acc = __builtin_amdgcn_mfma_f32_16x16x32_bf16(afrag[kc], bl8, acc, 0, 0, 0);
        }
#pragma unroll
        for (int reg = 0; reg < 4; ++reg) {
            int i = m_base + quad * 4 + reg;  // D: row = quad*4+reg
            int c = wave * 32 + ct * 16 + r;  // D: col = lane&15
            if (i < N) {
                float v = acc[reg];
                if (MODE == 0) v *= dinv[i];
                else v = tanhf(v + bias[c]);
                out[(size_t)i * 128 + c] = f2b(v);
            }
        }
    }
}

// ---------------- Aggregation: h[i] = tanh(dinv_i*(sum_e z[src_e] + 2 z_i) + b) --------
// One wave per node; lane handles channels 2*lane, 2*lane+1 (one packed uint).

__global__ __launch_bounds__(256) void agg_tanh_k(
    const uint32* __restrict__ z, const int* __restrict__ rowp,
    const int* __restrict__ csr, const float* __restrict__ dinv,
    const float* __restrict__ bias, uint32* __restrict__ out, int N) {
    int lane = threadIdx.x & 63;
    int i = blockIdx.x * 4 + (threadIdx.x >> 6);
    if (i >= N) return;
    int start = rowp[i], end = rowp[i + 1];
    float a0 = 0.f, a1 = 0.f;
    for (int e = start; e < end; e += 64) {
        int cnt = end - e;
        if (cnt > 64) cnt = 64;
        int s = (lane < cnt) ? csr[e + lane] : 0;
        for (int j = 0; j < cnt; ++j) {
            int sj = __shfl(s, j);
            uint32 v = z[(size_t)sj * 64 + lane];
            a0 += bl(v);
            a1 += bh(v);
        }
    }
    uint32 vi = z[(size_t)i * 64 + lane];
    a0 += 2.f * bl(vi);
    a1 += 2.f * bh(vi);
    float di = dinv[i];
    float bv0 = bias[2 * lane], bv1 = bias[2 * lane + 1];
    float h0 = tanhf(di * a0 + bv0);
    float h1 = tanhf(di * a1 + bv1);
    out[(size_t)i * 64 + lane] = (uint32)f2b(h0) | ((uint32)f2b(h1) << 16);
}

// ---------------- Final layer: out[N,3] = H @ lw4 + lb4 (fp32 out) ----------------

__global__ __launch_bounds__(256) void final_k(const unsigned short* __restrict__ H,
                                               const float* __restrict__ W4,
                                               const float* __restrict__ b4,
                                               float* __restrict__ out, int N) {
    __shared__ float wsm[128][3];
    int tid = threadIdx.x;
    if (tid < 128) {
#pragma unroll
        for (int c = 0; c < 3; ++c) wsm[tid][c] = W4[tid * 3 + c];
    }
    __syncthreads();
    int i = blockIdx.x * 256 + tid;
    if (i >= N) return;
    const uint32* hp = (const uint32*)(H + (size_t)i * 128);
    float acc0 = b4[0], acc1 = b4[1], acc2 = b4[2];
    for (int w = 0; w < 64; ++w) {
        uint32 v = hp[w];
        float x0 = bl(v), x1 = bh(v);
        acc0 += x0 * wsm[2 * w][0] + x1 * wsm[2 * w + 1][0];
        acc1 += x0 * wsm[2 * w][1] + x1 * wsm[2 * w + 1][1];
        acc2 += x0 * wsm[2 * w][2] + x1 * wsm[2 * w + 1][2];
    }
    out[(size_t)i * 3 + 0] = acc0;
    out[(size_t)i * 3 + 1] = acc1;
    out[(size_t)i * 3 + 2] = acc2;
}

extern "C" void kernel_launch(void* const* d_in, const int* in_sizes, int n_in,
                              void* d_out, int out_size, void* d_ws, size_t ws_size,
                              hipStream_t stream) {
    const float* x   = (const float*)d_in[0];
    const int* eidx  = (const int*)d_in[1];
    const float* W1  = (const float*)d_in[2];
    const float* b1  = (const float*)d_in[3];
    const float* W2  = (const float*)d_in[4];
    const float* b2  = (const float*)d_in[5];
    const float* lw1 = (const float*)d_in[6];
    const float* lb1 = (const float*)d_in[7];
    const float* lw2 = (const float*)d_in[8];
    const float* lb2 = (const float*)d_in[9];
    const float* lw3 = (const float*)d_in[10];
    const float* lb3 = (const float*)d_in[11];
    const float* lw4 = (const float*)d_in[12];
    const float* lb4 = (const float*)d_in[13];
    float* out = (float*)d_out;

    const int N = in_sizes[0] / 128;
    const int E = in_sizes[1] / 2;

    // workspace carve (256B aligned); total ~65.4 MB
    char* p = (char*)d_ws;
    auto alloc = [&](size_t bytes) -> void* {
        void* q = (void*)p;
        p += (bytes + 255) & ~(size_t)255;
        return q;
    };
    float* dinv = (float*)alloc((size_t)N * 4);
    int* cnt    = (int*)alloc((size_t)N * 4);
    int* rowp   = (int*)alloc((size_t)(N + 1) * 4);
    int* bsum   = (int*)alloc(1024 * 4);
    int* boff   = (int*)alloc(1024 * 4);
    int* csr    = (int*)alloc((size_t)E * 4);
    unsigned short* Wt_hi = (unsigned short*)alloc(128 * 128 * 2);
    unsigned short* Wt_lo = (unsigned short*)alloc(128 * 128 * 2);
    unsigned short* bufA  = (unsigned short*)alloc((size_t)N * 128 * 2);
    unsigned short* bufB  = (unsigned short*)alloc((size_t)N * 128 * 2);

    const int NB = (N + 255) / 256;
    const int EB = (E + 255) / 256;
    const int MB = (N + 15) / 16;
    const int AB = (N + 3) / 4;

    hipMemsetAsync(cnt, 0, (size_t)N * 4, stream);
    hist_k<<<EB, 256, 0, stream>>>(eidx, cnt, E);
    dinv_k<<<NB, 256, 0, stream>>>(cnt, dinv, N);
    scanA_k<<<NB, 256, 0, stream>>>(cnt, bsum, N);
    scanB_k<<<1, 512, 0, stream>>>(bsum, boff, NB);
    scanC_k<<<NB, 256, 0, stream>>>(cnt, boff, rowp, N, E);
    fill_k<<<EB, 256, 0, stream>>>(eidx, cnt, csr, E);

    // conv1: z1 = dinv * (x @ W1) ; h1 = tanh(dinv*(sum z1 + 2 z1_i) + b1)
    prep_w_k<<<64, 256, 0, stream>>>(W1, Wt_hi, Wt_lo);
    gemm128_k<0, 0><<<MB, 256, 0, stream>>>(x, Wt_hi, Wt_lo, dinv, nullptr, bufA, N);
    agg_tanh_k<<<AB, 256, 0, stream>>>((const uint32*)bufA, rowp, csr, dinv, b1,
                                       (uint32*)bufB, N);
    // conv2
    prep_w_k<<<64, 256, 0, stream>>>(W2, Wt_hi, Wt_lo);
    gemm128_k<1, 0><<<MB, 256, 0, stream>>>(bufB, Wt_hi, Wt_lo, dinv, nullptr, bufA, N);
    agg_tanh_k<<<AB, 256, 0, stream>>>((const uint32*)bufA, rowp, csr, dinv, b2,
                                       (uint32*)bufB, N);
    // MLP
    prep_w_k<<<64, 256, 0, stream>>>(lw1, Wt_hi, Wt_lo);
    gemm128_k<1, 1><<<MB, 256, 0, stream>>>(bufB, Wt_hi, Wt_lo, nullptr, lb1, bufA, N);
    prep_w_k<<<64, 256, 0, stream>>>(lw2, Wt_hi, Wt_lo);
    gemm128_k<1, 1><<<MB, 256, 0, stream>>>(bufA, Wt_hi, Wt_lo, nullptr, lb2, bufB, N);
    prep_w_k<<<64, 256, 0, stream>>>(lw3, Wt_hi, Wt_lo);
    gemm128_k<1, 1><<<MB, 256, 0, stream>>>(bufB, Wt_hi, Wt_lo, nullptr, lb3, bufA, N);
    final_k<<<NB, 256, 0, stream>>>(bufA, lw4, lb4, out, N);
}

// Round 3
// 916.714 us; speedup vs baseline: 1.3441x; 1.3441x over previous
//
#include <hip/hip_runtime.h>

typedef __attribute__((ext_vector_type(8))) short short8;
typedef __attribute__((ext_vector_type(4))) float floatx4;
typedef unsigned int uint32;

__device__ inline float b2f(unsigned short u) {
    union { uint32 i; float f; } x; x.i = ((uint32)u) << 16; return x.f;
}
__device__ inline float bl(uint32 v) {
    union { uint32 i; float f; } x; x.i = v << 16; return x.f;
}
__device__ inline float bh(uint32 v) {
    union { uint32 i; float f; } x; x.i = v & 0xffff0000u; return x.f;
}
__device__ inline unsigned short f2b(float f) {
    union { float f; uint32 u; } x; x.f = f;
    uint32 r = x.u + 0x7fffu + ((x.u >> 16) & 1u);
    return (unsigned short)(r >> 16);
}

// ================= CSR build via 2-level bucket sort =================
// bucket b owns nodes [b*256, b*256+255]; csr layout is bucket-major ==
// dst-major, so bucket bases double as csr row-pointer bases.
// packed edge word: (src << 8) | (dst & 255)   (requires N < 2^24)

#define CHUNK 8192
#define MAXBK 512  // supports N <= 131072

// --- phase A: count bucket sizes (per-block LDS hist -> global atomics) ---
__global__ __launch_bounds__(256) void countb_k(const int* __restrict__ eidx,
                                                uint32* __restrict__ bkt_size, int E) {
    __shared__ uint32 hist[MAXBK];
    int t = threadIdx.x;
    hist[t] = 0; hist[t + 256] = 0;
    __syncthreads();
    int base = blockIdx.x * CHUNK;
    int n = E - base; if (n > CHUNK) n = CHUNK;
    for (int i = t; i < n; i += 256) {
        int d = eidx[E + base + i];
        atomicAdd(&hist[d >> 8], 1u);
    }
    __syncthreads();
    uint32 c0 = hist[t], c1 = hist[t + 256];
    if (c0) atomicAdd(&bkt_size[t], c0);
    if (c1) atomicAdd(&bkt_size[t + 256], c1);
}

// --- phase B: exclusive scan of bucket sizes -> bkt_base, bkt_cur ---
__global__ __launch_bounds__(MAXBK) void scanb_k(const uint32* __restrict__ bkt_size,
                                                 uint32* __restrict__ bkt_base,
                                                 uint32* __restrict__ bkt_cur, int nbk) {
    __shared__ uint32 s[MAXBK];
    int t = threadIdx.x;
    uint32 v = (t < nbk) ? bkt_size[t] : 0;
    s[t] = v;
    __syncthreads();
    for (int off = 1; off < MAXBK; off <<= 1) {
        uint32 x = (t >= off) ? s[t - off] : 0;
        __syncthreads();
        s[t] += x;
        __syncthreads();
    }
    uint32 excl = s[t] - v;
    bkt_base[t] = excl;
    bkt_cur[t] = excl;
}

// --- phase C: scatter edges into bucket segments (LDS-staged, coalesced) ---
__global__ __launch_bounds__(256) void scatterb_k(const int* __restrict__ eidx,
                                                  uint32* __restrict__ bkt_cur,
                                                  uint32* __restrict__ packed, int E) {
    __shared__ uint32 hist[MAXBK];
    __shared__ uint32 temp[256];
    __shared__ uint32 hsc[MAXBK + 1];
    __shared__ uint32 gbase[MAXBK];
    __shared__ uint32 lcur[MAXBK];
    __shared__ uint32 stage[CHUNK];
    int t = threadIdx.x;
    int cbase = blockIdx.x * CHUNK;
    int n = E - cbase; if (n > CHUNK) n = CHUNK;

    hist[t] = 0; hist[t + 256] = 0;
    __syncthreads();
    for (int i = t; i < n; i += 256) {
        int d = eidx[E + cbase + i];
        atomicAdd(&hist[d >> 8], 1u);
    }
    __syncthreads();
    // pair-based exclusive scan of hist[512] -> hsc[513]
    uint32 c0 = hist[2 * t], c1 = hist[2 * t + 1];
    temp[t] = c0 + c1;
    __syncthreads();
    for (int off = 1; off < 256; off <<= 1) {
        uint32 x = (t >= off) ? temp[t - off] : 0;
        __syncthreads();
        temp[t] += x;
        __syncthreads();
    }
    uint32 exclp = temp[t] - (c0 + c1);
    hsc[2 * t] = exclp;
    hsc[2 * t + 1] = exclp + c0;
    if (t == 255) hsc[MAXBK] = temp[255];
    // reserve global segments + init local cursors
    lcur[2 * t] = exclp;
    lcur[2 * t + 1] = exclp + c0;
    if (c0) gbase[2 * t] = atomicAdd(&bkt_cur[2 * t], c0);
    if (c1) gbase[2 * t + 1] = atomicAdd(&bkt_cur[2 * t + 1], c1);
    __syncthreads();
    // place packed edges into LDS stage, bucket-grouped
    for (int i = t; i < n; i += 256) {
        int s = eidx[cbase + i];
        int d = eidx[E + cbase + i];
        int b = d >> 8;
        uint32 pos = atomicAdd(&lcur[b], 1u);
        stage[pos] = ((uint32)s << 8) | (uint32)(d & 255);
    }
    __syncthreads();
    // write out: consecutive threads -> consecutive addresses within segment
    for (int i = t; i < n; i += 256) {
        // largest b with hsc[b] <= i
        int lo = 0, hi = MAXBK - 1;
        while (lo < hi) {
            int mid = (lo + hi + 1) >> 1;
            if (hsc[mid] <= (uint32)i) lo = mid; else hi = mid - 1;
        }
        packed[gbase[lo] + (i - hsc[lo])] = stage[i];
    }
}

// --- phase D: per-bucket CSR finalize + degrees + rowp + dinv ---
__global__ __launch_bounds__(256) void buildb_k(const uint32* __restrict__ packed,
                                                const uint32* __restrict__ bkt_base,
                                                const uint32* __restrict__ bkt_size,
                                                int* __restrict__ rowp,
                                                float* __restrict__ dinv,
                                                int* __restrict__ csr, int N, int E) {
    __shared__ uint32 cnt[256];
    __shared__ uint32 incl[256];
    __shared__ uint32 cur[256];
    int t = threadIdx.x;
    int b = blockIdx.x;
    uint32 base = bkt_base[b];
    uint32 size = bkt_size[b];
    int node0 = b << 8;

    cnt[t] = 0;
    __syncthreads();
    for (uint32 i = t; i < size; i += 256)
        atomicAdd(&cnt[packed[base + i] & 255u], 1u);
    __syncthreads();
    uint32 v = cnt[t];
    incl[t] = v;
    __syncthreads();
    for (int off = 1; off < 256; off <<= 1) {
        uint32 x = (t >= off) ? incl[t - off] : 0;
        __syncthreads();
        incl[t] += x;
        __syncthreads();
    }
    uint32 loc = incl[t] - v;  // exclusive
    cur[t] = loc;
    int node = node0 + t;
    if (node < N) {
        dinv[node] = rsqrtf((float)v + 2.0f);
        rowp[node] = (int)(base + loc);
        if (node == N - 1) rowp[N] = E;
    }
    __syncthreads();
    for (uint32 i = t; i < size; i += 256) {
        uint32 p = packed[base + i];
        uint32 pos = atomicAdd(&cur[p & 255u], 1u);
        csr[base + pos] = (int)(p >> 8);
    }
}

// ---------------- weight prep: W fp32 [128][128] -> Wt_hi/Wt_lo bf16 (transposed) ----

__global__ __launch_bounds__(256) void prep_w_k(const float* __restrict__ W,
                                                unsigned short* __restrict__ Wt_hi,
                                                unsigned short* __restrict__ Wt_lo) {
    int t = blockIdx.x * 256 + threadIdx.x;  // 64 blocks
    int c = t & 127, k = t >> 7;
    float w = W[k * 128 + c];
    unsigned short hi = f2b(w);
    float lo = w - b2f(hi);
    Wt_hi[c * 128 + k] = hi;
    Wt_lo[c * 128 + k] = f2b(lo);
}

// ---------------- GEMM (128-wide, MFMA 16x16x32 bf16, split-W for fp32 accuracy) ----
// ASRC 0: A is fp32 (convert to bf16 in-flight)    ASRC 1: A is bf16 storage
// MODE 0: out = dinv[i] * (A @ W)   (z for conv)   MODE 1: out = tanh(A @ W + bias)

template <int ASRC, int MODE>
__global__ __launch_bounds__(256) void gemm128_k(
    const void* __restrict__ Asrc,
    const unsigned short* __restrict__ Wt_hi,
    const unsigned short* __restrict__ Wt_lo,
    const float* __restrict__ dinv, const float* __restrict__ bias,
    unsigned short* __restrict__ out, int N) {
    int tid = threadIdx.x;
    int wave = tid >> 6, lane = tid & 63;
    int quad = lane >> 4, r = lane & 15;
    int m_base = blockIdx.x * 16;

    int rowA = m_base + r;
    if (rowA >= N) rowA = N - 1;  // clamp (stores guarded below)

    short8 afrag[4];
    if (ASRC == 0) {
        const float* Af = (const float*)Asrc;
#pragma unroll
        for (int kc = 0; kc < 4; ++kc) {
            const float* p = Af + (size_t)rowA * 128 + kc * 32 + quad * 8;
            short8 a;
#pragma unroll
            for (int j = 0; j < 8; ++j) a[j] = (short)f2b(p[j]);
            afrag[kc] = a;
        }
    } else {
        const short* Ap = (const short*)Asrc;
#pragma unroll
        for (int kc = 0; kc < 4; ++kc)
            afrag[kc] = *(const short8*)(Ap + (size_t)rowA * 128 + kc * 32 + quad * 8);
    }

    const short* Wh = (const short*)Wt_hi;
    const short* Wl = (const short*)Wt_lo;

#pragma unroll
    for (int ct = 0; ct < 2; ++ct) {
        int n = wave * 32 + ct * 16 + r;
        floatx4 acc = {0.f, 0.f, 0.f, 0.f};
#pragma unroll
        for (int kc = 0; kc < 4; ++kc) {
            short8 bh8 = *(const short8*)(Wh + n * 128 + kc * 32 + quad * 8);
            acc = __builtin_amdgcn_mfma_f32_16x16x32_bf16(afrag[kc], bh8, acc, 0, 0, 0);
            short8 bl8 = *(const short8*)(Wl + n * 128 + kc * 32 + quad * 8);
            acc = __builtin_amdgcn_mfma_f32_16x16x32_bf16(afrag[kc], bl8, acc, 0, 0, 0);
        }
#pragma unroll
        for (int reg = 0; reg < 4; ++reg) {
            int i = m_base + quad * 4 + reg;  // D: row = quad*4+reg
            int c = wave * 32 + ct * 16 + r;  // D: col = lane&15
            if (i < N) {
                float v = acc[reg];
                if (MODE == 0) v *= dinv[i];
                else v = tanhf(v + bias[c]);
                out[(size_t)i * 128 + c] = f2b(v);
            }
        }
    }
}

// ---------------- Aggregation: h[i] = tanh(dinv_i*(sum_e z[src_e] + 2 z_i) + b) --------
// One wave per node; lane handles channels 2*lane, 2*lane+1 (one packed uint).

__global__ __launch_bounds__(256) void agg_tanh_k(
    const uint32* __restrict__ z, const int* __restrict__ rowp,
    const int* __restrict__ csr, const float* __restrict__ dinv,
    const float* __restrict__ bias, uint32* __restrict__ out, int N) {
    int lane = threadIdx.x & 63;
    int i = blockIdx.x * 4 + (threadIdx.x >> 6);
    if (i >= N) return;
    int start = rowp[i], end = rowp[i + 1];
    float a0 = 0.f, a1 = 0.f;
    for (int e = start; e < end; e += 64) {
        int cnt = end - e;
        if (cnt > 64) cnt = 64;
        int s = (lane < cnt) ? csr[e + lane] : 0;
        for (int j = 0; j < cnt; ++j) {
            int sj = __shfl(s, j);
            uint32 v = z[(size_t)sj * 64 + lane];
            a0 += bl(v);
            a1 += bh(v);
        }
    }
    uint32 vi = z[(size_t)i * 64 + lane];
    a0 += 2.f * bl(vi);
    a1 += 2.f * bh(vi);
    float di = dinv[i];
    float bv0 = bias[2 * lane], bv1 = bias[2 * lane + 1];
    float h0 = tanhf(di * a0 + bv0);
    float h1 = tanhf(di * a1 + bv1);
    out[(size_t)i * 64 + lane] = (uint32)f2b(h0) | ((uint32)f2b(h1) << 16);
}

// ---------------- Final layer: out[N,3] = H @ lw4 + lb4 (fp32 out) ----------------

__global__ __launch_bounds__(256) void final_k(const unsigned short* __restrict__ H,
                                               const float* __restrict__ W4,
                                               const float* __restrict__ b4,
                                               float* __restrict__ out, int N) {
    __shared__ float wsm[128][3];
    int tid = threadIdx.x;
    if (tid < 128) {
#pragma unroll
        for (int c = 0; c < 3; ++c) wsm[tid][c] = W4[tid * 3 + c];
    }
    __syncthreads();
    int i = blockIdx.x * 256 + tid;
    if (i >= N) return;
    const uint32* hp = (const uint32*)(H + (size_t)i * 128);
    float acc0 = b4[0], acc1 = b4[1], acc2 = b4[2];
    for (int w = 0; w < 64; ++w) {
        uint32 v = hp[w];
        float x0 = bl(v), x1 = bh(v);
        acc0 += x0 * wsm[2 * w][0] + x1 * wsm[2 * w + 1][0];
        acc1 += x0 * wsm[2 * w][1] + x1 * wsm[2 * w + 1][1];
        acc2 += x0 * wsm[2 * w][2] + x1 * wsm[2 * w + 1][2];
    }
    out[(size_t)i * 3 + 0] = acc0;
    out[(size_t)i * 3 + 1] = acc1;
    out[(size_t)i * 3 + 2] = acc2;
}

extern "C" void kernel_launch(void* const* d_in, const int* in_sizes, int n_in,
                              void* d_out, int out_size, void* d_ws, size_t ws_size,
                              hipStream_t stream) {
    const float* x   = (const float*)d_in[0];
    const int* eidx  = (const int*)d_in[1];
    const float* W1  = (const float*)d_in[2];
    const float* b1  = (const float*)d_in[3];
    const float* W2  = (const float*)d_in[4];
    const float* b2  = (const float*)d_in[5];
    const float* lw1 = (const float*)d_in[6];
    const float* lb1 = (const float*)d_in[7];
    const float* lw2 = (const float*)d_in[8];
    const float* lb2 = (const float*)d_in[9];
    const float* lw3 = (const float*)d_in[10];
    const float* lb3 = (const float*)d_in[11];
    const float* lw4 = (const float*)d_in[12];
    const float* lb4 = (const float*)d_in[13];
    float* out = (float*)d_out;

    const int N = in_sizes[0] / 128;
    const int E = in_sizes[1] / 2;

    // workspace carve (256B aligned); total ~64.9 MB
    char* p = (char*)d_ws;
    auto alloc = [&](size_t bytes) -> void* {
        void* q = (void*)p;
        p += (bytes + 255) & ~(size_t)255;
        return q;
    };
    float* dinv      = (float*)alloc((size_t)N * 4);
    int* rowp        = (int*)alloc((size_t)(N + 1) * 4);
    uint32* bkt_size = (uint32*)alloc(MAXBK * 4);
    uint32* bkt_base = (uint32*)alloc(MAXBK * 4);
    uint32* bkt_cur  = (uint32*)alloc(MAXBK * 4);
    int* csr         = (int*)alloc((size_t)E * 4);
    unsigned short* Wt_hi = (unsigned short*)alloc(128 * 128 * 2);
    unsigned short* Wt_lo = (unsigned short*)alloc(128 * 128 * 2);
    unsigned short* bufA  = (unsigned short*)alloc((size_t)N * 128 * 2);
    unsigned short* bufB  = (unsigned short*)alloc((size_t)N * 128 * 2);
    uint32* packed = (uint32*)bufA;  // alias: packed (E*4 B) dead before gemm1 writes bufA

    const int NB  = (N + 255) / 256;
    const int MB  = (N + 15) / 16;
    const int AB  = (N + 3) / 4;
    const int NCH = (E + CHUNK - 1) / CHUNK;
    const int NBK = (N + 255) >> 8;  // must be <= MAXBK

    // CSR build (bucket sort)
    hipMemsetAsync(bkt_size, 0, MAXBK * 4, stream);
    countb_k<<<NCH, 256, 0, stream>>>(eidx, bkt_size, E);
    scanb_k<<<1, MAXBK, 0, stream>>>(bkt_size, bkt_base, bkt_cur, NBK);
    scatterb_k<<<NCH, 256, 0, stream>>>(eidx, bkt_cur, packed, E);
    buildb_k<<<NBK, 256, 0, stream>>>(packed, bkt_base, bkt_size, rowp, dinv, csr, N, E);

    // conv1: z1 = dinv * (x @ W1) ; h1 = tanh(dinv*(sum z1 + 2 z1_i) + b1)
    prep_w_k<<<64, 256, 0, stream>>>(W1, Wt_hi, Wt_lo);
    gemm128_k<0, 0><<<MB, 256, 0, stream>>>(x, Wt_hi, Wt_lo, dinv, nullptr, bufA, N);
    agg_tanh_k<<<AB, 256, 0, stream>>>((const uint32*)bufA, rowp, csr, dinv, b1,
                                       (uint32*)bufB, N);
    // conv2
    prep_w_k<<<64, 256, 0, stream>>>(W2, Wt_hi, Wt_lo);
    gemm128_k<1, 0><<<MB, 256, 0, stream>>>(bufB, Wt_hi, Wt_lo, dinv, nullptr, bufA, N);
    agg_tanh_k<<<AB, 256, 0, stream>>>((const uint32*)bufA, rowp, csr, dinv, b2,
                                       (uint32*)bufB, N);
    // MLP
    prep_w_k<<<64, 256, 0, stream>>>(lw1, Wt_hi, Wt_lo);
    gemm128_k<1, 1><<<MB, 256, 0, stream>>>(bufB, Wt_hi, Wt_lo, nullptr, lb1, bufA, N);
    prep_w_k<<<64, 256, 0, stream>>>(lw2, Wt_hi, Wt_lo);
    gemm128_k<1, 1><<<MB, 256, 0, stream>>>(bufA, Wt_hi, Wt_lo, nullptr, lb2, bufB, N);
    prep_w_k<<<64, 256, 0, stream>>>(lw3, Wt_hi, Wt_lo);
    gemm128_k<1, 1><<<MB, 256, 0, stream>>>(bufB, Wt_hi, Wt_lo, nullptr, lb3, bufA, N);
    final_k<<<NB, 256, 0, stream>>>(bufA, lw4, lb4, out, N);
}

// Round 4
// 755.167 us; speedup vs baseline: 1.6316x; 1.2139x over previous
//
#include <hip/hip_runtime.h>

typedef __attribute__((ext_vector_type(8))) short short8;
typedef __attribute__((ext_vector_type(4))) float floatx4;
typedef __attribute__((ext_vector_type(2))) unsigned int uintx2;
typedef unsigned int uint32;

__device__ inline float b2f(unsigned short u) {
    union { uint32 i; float f; } x; x.i = ((uint32)u) << 16; return x.f;
}
__device__ inline float bl(uint32 v) {
    union { uint32 i; float f; } x; x.i = v << 16; return x.f;
}
__device__ inline float bh(uint32 v) {
    union { uint32 i; float f; } x; x.i = v & 0xffff0000u; return x.f;
}
__device__ inline unsigned short f2b(float f) {
    union { float f; uint32 u; } x; x.f = f;
    uint32 r = x.u + 0x7fffu + ((x.u >> 16) & 1u);
    return (unsigned short)(r >> 16);
}

// ================= CSR build via 2-level bucket sort =================
// bucket b owns nodes [b*256, b*256+255]; csr layout is bucket-major ==
// dst-major, so bucket bases double as csr row-pointer bases.
// packed edge word: (src << 8) | (dst & 255)   (requires N < 2^24)

#define CHUNK 8192
#define MAXBK 512  // supports N <= 131072

// --- phase A: count bucket sizes (per-block LDS hist -> global atomics) ---
__global__ __launch_bounds__(256) void countb_k(const int* __restrict__ eidx,
                                                uint32* __restrict__ bkt_size, int E) {
    __shared__ uint32 hist[MAXBK];
    int t = threadIdx.x;
    hist[t] = 0; hist[t + 256] = 0;
    __syncthreads();
    int base = blockIdx.x * CHUNK;
    int n = E - base; if (n > CHUNK) n = CHUNK;
    for (int i = t; i < n; i += 256) {
        int d = eidx[E + base + i];
        atomicAdd(&hist[d >> 8], 1u);
    }
    __syncthreads();
    uint32 c0 = hist[t], c1 = hist[t + 256];
    if (c0) atomicAdd(&bkt_size[t], c0);
    if (c1) atomicAdd(&bkt_size[t + 256], c1);
}

// --- phase B: exclusive scan of bucket sizes -> bkt_base, bkt_cur ---
__global__ __launch_bounds__(MAXBK) void scanb_k(const uint32* __restrict__ bkt_size,
                                                 uint32* __restrict__ bkt_base,
                                                 uint32* __restrict__ bkt_cur, int nbk) {
    __shared__ uint32 s[MAXBK];
    int t = threadIdx.x;
    uint32 v = (t < nbk) ? bkt_size[t] : 0;
    s[t] = v;
    __syncthreads();
    for (int off = 1; off < MAXBK; off <<= 1) {
        uint32 x = (t >= off) ? s[t - off] : 0;
        __syncthreads();
        s[t] += x;
        __syncthreads();
    }
    uint32 excl = s[t] - v;
    bkt_base[t] = excl;
    bkt_cur[t] = excl;
}

// --- phase C: scatter edges into bucket segments (LDS-staged, coalesced) ---
__global__ __launch_bounds__(256) void scatterb_k(const int* __restrict__ eidx,
                                                  uint32* __restrict__ bkt_cur,
                                                  uint32* __restrict__ packed, int E) {
    __shared__ uint32 hist[MAXBK];
    __shared__ uint32 temp[256];
    __shared__ uint32 hsc[MAXBK + 1];
    __shared__ uint32 gbase[MAXBK];
    __shared__ uint32 lcur[MAXBK];
    __shared__ uint32 stage[CHUNK];
    int t = threadIdx.x;
    int cbase = blockIdx.x * CHUNK;
    int n = E - cbase; if (n > CHUNK) n = CHUNK;

    hist[t] = 0; hist[t + 256] = 0;
    __syncthreads();
    for (int i = t; i < n; i += 256) {
        int d = eidx[E + cbase + i];
        atomicAdd(&hist[d >> 8], 1u);
    }
    __syncthreads();
    // pair-based exclusive scan of hist[512] -> hsc[513]
    uint32 c0 = hist[2 * t], c1 = hist[2 * t + 1];
    temp[t] = c0 + c1;
    __syncthreads();
    for (int off = 1; off < 256; off <<= 1) {
        uint32 x = (t >= off) ? temp[t - off] : 0;
        __syncthreads();
        temp[t] += x;
        __syncthreads();
    }
    uint32 exclp = temp[t] - (c0 + c1);
    hsc[2 * t] = exclp;
    hsc[2 * t + 1] = exclp + c0;
    if (t == 255) hsc[MAXBK] = temp[255];
    // reserve global segments + init local cursors
    lcur[2 * t] = exclp;
    lcur[2 * t + 1] = exclp + c0;
    if (c0) gbase[2 * t] = atomicAdd(&bkt_cur[2 * t], c0);
    if (c1) gbase[2 * t + 1] = atomicAdd(&bkt_cur[2 * t + 1], c1);
    __syncthreads();
    // place packed edges into LDS stage, bucket-grouped
    for (int i = t; i < n; i += 256) {
        int s = eidx[cbase + i];
        int d = eidx[E + cbase + i];
        int b = d >> 8;
        uint32 pos = atomicAdd(&lcur[b], 1u);
        stage[pos] = ((uint32)s << 8) | (uint32)(d & 255);
    }
    __syncthreads();
    // write out: consecutive threads -> consecutive addresses within segment
    for (int i = t; i < n; i += 256) {
        // largest b with hsc[b] <= i
        int lo = 0, hi = MAXBK - 1;
        while (lo < hi) {
            int mid = (lo + hi + 1) >> 1;
            if (hsc[mid] <= (uint32)i) lo = mid; else hi = mid - 1;
        }
        packed[gbase[lo] + (i - hsc[lo])] = stage[i];
    }
}

// --- phase D: per-bucket CSR finalize + degrees + rowp + dinv ---
__global__ __launch_bounds__(256) void buildb_k(const uint32* __restrict__ packed,
                                                const uint32* __restrict__ bkt_base,
                                                const uint32* __restrict__ bkt_size,
                                                int* __restrict__ rowp,
                                                float* __restrict__ dinv,
                                                int* __restrict__ csr, int N, int E) {
    __shared__ uint32 cnt[256];
    __shared__ uint32 incl[256];
    __shared__ uint32 cur[256];
    int t = threadIdx.x;
    int b = blockIdx.x;
    uint32 base = bkt_base[b];
    uint32 size = bkt_size[b];
    int node0 = b << 8;

    cnt[t] = 0;
    __syncthreads();
    for (uint32 i = t; i < size; i += 256)
        atomicAdd(&cnt[packed[base + i] & 255u], 1u);
    __syncthreads();
    uint32 v = cnt[t];
    incl[t] = v;
    __syncthreads();
    for (int off = 1; off < 256; off <<= 1) {
        uint32 x = (t >= off) ? incl[t - off] : 0;
        __syncthreads();
        incl[t] += x;
        __syncthreads();
    }
    uint32 loc = incl[t] - v;  // exclusive
    cur[t] = loc;
    int node = node0 + t;
    if (node < N) {
        dinv[node] = rsqrtf((float)v + 2.0f);
        rowp[node] = (int)(base + loc);
        if (node == N - 1) rowp[N] = E;
    }
    __syncthreads();
    for (uint32 i = t; i < size; i += 256) {
        uint32 p = packed[base + i];
        uint32 pos = atomicAdd(&cur[p & 255u], 1u);
        csr[base + pos] = (int)(p >> 8);
    }
}

// ---------------- weight prep: W fp32 [128][128] -> Wt_hi/Wt_lo bf16 (transposed) ----

__global__ __launch_bounds__(256) void prep_w_k(const float* __restrict__ W,
                                                unsigned short* __restrict__ Wt_hi,
                                                unsigned short* __restrict__ Wt_lo) {
    int t = blockIdx.x * 256 + threadIdx.x;  // 64 blocks
    int c = t & 127, k = t >> 7;
    float w = W[k * 128 + c];
    unsigned short hi = f2b(w);
    float lo = w - b2f(hi);
    Wt_hi[c * 128 + k] = hi;
    Wt_lo[c * 128 + k] = f2b(lo);
}

// ---------------- GEMM (128-wide, MFMA 16x16x32 bf16, split-W for fp32 accuracy) ----
// ASRC 0: A is fp32 (convert to bf16 in-flight)    ASRC 1: A is bf16 storage
// MODE 0: out = dinv[i] * (A @ W)   (z for conv)   MODE 1: out = tanh(A @ W + bias)

template <int ASRC, int MODE>
__global__ __launch_bounds__(256) void gemm128_k(
    const void* __restrict__ Asrc,
    const unsigned short* __restrict__ Wt_hi,
    const unsigned short* __restrict__ Wt_lo,
    const float* __restrict__ dinv, const float* __restrict__ bias,
    unsigned short* __restrict__ out, int N) {
    int tid = threadIdx.x;
    int wave = tid >> 6, lane = tid & 63;
    int quad = lane >> 4, r = lane & 15;
    int m_base = blockIdx.x * 16;

    int rowA = m_base + r;
    if (rowA >= N) rowA = N - 1;  // clamp (stores guarded below)

    short8 afrag[4];
    if (ASRC == 0) {
        const float* Af = (const float*)Asrc;
#pragma unroll
        for (int kc = 0; kc < 4; ++kc) {
            const float* p = Af + (size_t)rowA * 128 + kc * 32 + quad * 8;
            short8 a;
#pragma unroll
            for (int j = 0; j < 8; ++j) a[j] = (short)f2b(p[j]);
            afrag[kc] = a;
        }
    } else {
        const short* Ap = (const short*)Asrc;
#pragma unroll
        for (int kc = 0; kc < 4; ++kc)
            afrag[kc] = *(const short8*)(Ap + (size_t)rowA * 128 + kc * 32 + quad * 8);
    }

    const short* Wh = (const short*)Wt_hi;
    const short* Wl = (const short*)Wt_lo;

#pragma unroll
    for (int ct = 0; ct < 2; ++ct) {
        int n = wave * 32 + ct * 16 + r;
        floatx4 acc = {0.f, 0.f, 0.f, 0.f};
#pragma unroll
        for (int kc = 0; kc < 4; ++kc) {
            short8 bh8 = *(const short8*)(Wh + n * 128 + kc * 32 + quad * 8);
            acc = __builtin_amdgcn_mfma_f32_16x16x32_bf16(afrag[kc], bh8, acc, 0, 0, 0);
            short8 bl8 = *(const short8*)(Wl + n * 128 + kc * 32 + quad * 8);
            acc = __builtin_amdgcn_mfma_f32_16x16x32_bf16(afrag[kc], bl8, acc, 0, 0, 0);
        }
#pragma unroll
        for (int reg = 0; reg < 4; ++reg) {
            int i = m_base + quad * 4 + reg;  // D: row = quad*4+reg
            int c = wave * 32 + ct * 16 + r;  // D: col = lane&15
            if (i < N) {
                float v = acc[reg];
                if (MODE == 0) v *= dinv[i];
                else v = tanhf(v + bias[c]);
                out[(size_t)i * 128 + c] = f2b(v);
            }
        }
    }
}

// ---------------- Aggregation: h[i] = tanh(dinv_i*(sum_e z[src_e] + 2 z_i) + b) --------
// One wave per node. Lanes 0-31 process even edges, lanes 32-63 odd edges;
// each lane covers 4 channels (uint2 = 8B). Chunks of 16 edges issue 8
// independent dwordx2 loads before any accumulate -> ~8 loads in flight/wave.

__global__ __launch_bounds__(256) void agg_tanh_k(
    const uint32* __restrict__ z, const int* __restrict__ rowp,
    const int* __restrict__ csr, const float* __restrict__ dinv,
    const float* __restrict__ bias, uint32* __restrict__ out, int N) {
    int lane = threadIdx.x & 63;
    int half = lane >> 5;   // 0: even edges, 1: odd edges
    int c4 = lane & 31;     // 4-channel group (channels 4*c4 .. 4*c4+3)
    int i = blockIdx.x * 4 + (threadIdx.x >> 6);
    if (i >= N) return;
    int start = rowp[i], end = rowp[i + 1];
    const uintx2* z2 = (const uintx2*)z;
    float a0 = 0.f, a1 = 0.f, a2 = 0.f, a3 = 0.f;
    for (int e = start; e < end; e += 64) {
        int cnt = end - e;
        if (cnt > 64) cnt = 64;
        int s = (lane < cnt) ? csr[e + lane] : 0;
        for (int m = 0; m < cnt; m += 16) {
            uintx2 v[8];
            float f[8];
#pragma unroll
            for (int p = 0; p < 8; ++p) {
                int idx = m + 2 * p + half;
                int sj = __shfl(s, idx);            // per-lane bpermute
                f[p] = (idx < cnt) ? 1.f : 0.f;
                v[p] = z2[(size_t)sj * 32 + c4];    // 8 loads in flight
            }
#pragma unroll
            for (int p = 0; p < 8; ++p) {
                a0 = fmaf(bl(v[p][0]), f[p], a0);
                a1 = fmaf(bh(v[p][0]), f[p], a1);
                a2 = fmaf(bl(v[p][1]), f[p], a2);
                a3 = fmaf(bh(v[p][1]), f[p], a3);
            }
        }
    }
    // combine even/odd halves (channels match across half-waves)
    a0 += __shfl_xor(a0, 32);
    a1 += __shfl_xor(a1, 32);
    a2 += __shfl_xor(a2, 32);
    a3 += __shfl_xor(a3, 32);
    if (half == 0) {
        uintx2 vi = z2[(size_t)i * 32 + c4];
        a0 += 2.f * bl(vi[0]);
        a1 += 2.f * bh(vi[0]);
        a2 += 2.f * bl(vi[1]);
        a3 += 2.f * bh(vi[1]);
        float di = dinv[i];
        float4 bv = ((const float4*)bias)[c4];
        float h0 = tanhf(fmaf(di, a0, bv.x));
        float h1 = tanhf(fmaf(di, a1, bv.y));
        float h2 = tanhf(fmaf(di, a2, bv.z));
        float h3 = tanhf(fmaf(di, a3, bv.w));
        uintx2 o;
        o[0] = (uint32)f2b(h0) | ((uint32)f2b(h1) << 16);
        o[1] = (uint32)f2b(h2) | ((uint32)f2b(h3) << 16);
        ((uintx2*)out)[(size_t)i * 32 + c4] = o;
    }
}

// ---------------- Final layer: out[N,3] = H @ lw4 + lb4 (fp32 out) ----------------

__global__ __launch_bounds__(256) void final_k(const unsigned short* __restrict__ H,
                                               const float* __restrict__ W4,
                                               const float* __restrict__ b4,
                                               float* __restrict__ out, int N) {
    __shared__ float wsm[128][3];
    int tid = threadIdx.x;
    if (tid < 128) {
#pragma unroll
        for (int c = 0; c < 3; ++c) wsm[tid][c] = W4[tid * 3 + c];
    }
    __syncthreads();
    int i = blockIdx.x * 256 + tid;
    if (i >= N) return;
    const uint32* hp = (const uint32*)(H + (size_t)i * 128);
    float acc0 = b4[0], acc1 = b4[1], acc2 = b4[2];
    for (int w = 0; w < 64; ++w) {
        uint32 v = hp[w];
        float x0 = bl(v), x1 = bh(v);
        acc0 += x0 * wsm[2 * w][0] + x1 * wsm[2 * w + 1][0];
        acc1 += x0 * wsm[2 * w][1] + x1 * wsm[2 * w + 1][1];
        acc2 += x0 * wsm[2 * w][2] + x1 * wsm[2 * w + 1][2];
    }
    out[(size_t)i * 3 + 0] = acc0;
    out[(size_t)i * 3 + 1] = acc1;
    out[(size_t)i * 3 + 2] = acc2;
}

extern "C" void kernel_launch(void* const* d_in, const int* in_sizes, int n_in,
                              void* d_out, int out_size, void* d_ws, size_t ws_size,
                              hipStream_t stream) {
    const float* x   = (const float*)d_in[0];
    const int* eidx  = (const int*)d_in[1];
    const float* W1  = (const float*)d_in[2];
    const float* b1  = (const float*)d_in[3];
    const float* W2  = (const float*)d_in[4];
    const float* b2  = (const float*)d_in[5];
    const float* lw1 = (const float*)d_in[6];
    const float* lb1 = (const float*)d_in[7];
    const float* lw2 = (const float*)d_in[8];
    const float* lb2 = (const float*)d_in[9];
    const float* lw3 = (const float*)d_in[10];
    const float* lb3 = (const float*)d_in[11];
    const float* lw4 = (const float*)d_in[12];
    const float* lb4 = (const float*)d_in[13];
    float* out = (float*)d_out;

    const int N = in_sizes[0] / 128;
    const int E = in_sizes[1] / 2;

    // workspace carve (256B aligned); total ~64.9 MB
    char* p = (char*)d_ws;
    auto alloc = [&](size_t bytes) -> void* {
        void* q = (void*)p;
        p += (bytes + 255) & ~(size_t)255;
        return q;
    };
    float* dinv      = (float*)alloc((size_t)N * 4);
    int* rowp        = (int*)alloc((size_t)(N + 1) * 4);
    uint32* bkt_size = (uint32*)alloc(MAXBK * 4);
    uint32* bkt_base = (uint32*)alloc(MAXBK * 4);
    uint32* bkt_cur  = (uint32*)alloc(MAXBK * 4);
    int* csr         = (int*)alloc((size_t)E * 4);
    unsigned short* Wt_hi = (unsigned short*)alloc(128 * 128 * 2);
    unsigned short* Wt_lo = (unsigned short*)alloc(128 * 128 * 2);
    unsigned short* bufA  = (unsigned short*)alloc((size_t)N * 128 * 2);
    unsigned short* bufB  = (unsigned short*)alloc((size_t)N * 128 * 2);
    uint32* packed = (uint32*)bufA;  // alias: packed (E*4 B) dead before gemm1 writes bufA

    const int NB  = (N + 255) / 256;
    const int MB  = (N + 15) / 16;
    const int AB  = (N + 3) / 4;
    const int NCH = (E + CHUNK - 1) / CHUNK;
    const int NBK = (N + 255) >> 8;  // must be <= MAXBK

    // CSR build (bucket sort)
    hipMemsetAsync(bkt_size, 0, MAXBK * 4, stream);
    countb_k<<<NCH, 256, 0, stream>>>(eidx, bkt_size, E);
    scanb_k<<<1, MAXBK, 0, stream>>>(bkt_size, bkt_base, bkt_cur, NBK);
    scatterb_k<<<NCH, 256, 0, stream>>>(eidx, bkt_cur, packed, E);
    buildb_k<<<NBK, 256, 0, stream>>>(packed, bkt_base, bkt_size, rowp, dinv, csr, N, E);

    // conv1: z1 = dinv * (x @ W1) ; h1 = tanh(dinv*(sum z1 + 2 z1_i) + b1)
    prep_w_k<<<64, 256, 0, stream>>>(W1, Wt_hi, Wt_lo);
    gemm128_k<0, 0><<<MB, 256, 0, stream>>>(x, Wt_hi, Wt_lo, dinv, nullptr, bufA, N);
    agg_tanh_k<<<AB, 256, 0, stream>>>((const uint32*)bufA, rowp, csr, dinv, b1,
                                       (uint32*)bufB, N);
    // conv2
    prep_w_k<<<64, 256, 0, stream>>>(W2, Wt_hi, Wt_lo);
    gemm128_k<1, 0><<<MB, 256, 0, stream>>>(bufB, Wt_hi, Wt_lo, dinv, nullptr, bufA, N);
    agg_tanh_k<<<AB, 256, 0, stream>>>((const uint32*)bufA, rowp, csr, dinv, b2,
                                       (uint32*)bufB, N);
    // MLP
    prep_w_k<<<64, 256, 0, stream>>>(lw1, Wt_hi, Wt_lo);
    gemm128_k<1, 1><<<MB, 256, 0, stream>>>(bufB, Wt_hi, Wt_lo, nullptr, lb1, bufA, N);
    prep_w_k<<<64, 256, 0, stream>>>(lw2, Wt_hi, Wt_lo);
    gemm128_k<1, 1><<<MB, 256, 0, stream>>>(bufA, Wt_hi, Wt_lo, nullptr, lb2, bufB, N);
    prep_w_k<<<64, 256, 0, stream>>>(lw3, Wt_hi, Wt_lo);
    gemm128_k<1, 1><<<MB, 256, 0, stream>>>(bufB, Wt_hi, Wt_lo, nullptr, lb3, bufA, N);
    final_k<<<NB, 256, 0, stream>>>(bufA, lw4, lb4, out, N);
}

// Round 5
// 716.093 us; speedup vs baseline: 1.7206x; 1.0546x over previous
//
#include <hip/hip_runtime.h>

typedef __attribute__((ext_vector_type(8))) short short8;
typedef __attribute__((ext_vector_type(4))) float floatx4;
typedef __attribute__((ext_vector_type(2))) unsigned int uintx2;
typedef unsigned int uint32;

__device__ inline float b2f(unsigned short u) {
    union { uint32 i; float f; } x; x.i = ((uint32)u) << 16; return x.f;
}
__device__ inline float bl(uint32 v) {
    union { uint32 i; float f; } x; x.i = v << 16; return x.f;
}
__device__ inline float bh(uint32 v) {
    union { uint32 i; float f; } x; x.i = v & 0xffff0000u; return x.f;
}
__device__ inline unsigned short f2b(float f) {
    union { float f; uint32 u; } x; x.f = f;
    uint32 r = x.u + 0x7fffu + ((x.u >> 16) & 1u);
    return (unsigned short)(r >> 16);
}

// ================= CSR build via 2-level bucket sort =================
// bucket b owns nodes [b*256, b*256+255]; csr layout is bucket-major ==
// dst-major, so bucket bases double as csr row-pointer bases.
// packed edge word: (src << 8) | (dst & 255)   (requires N < 2^24)

#define CHUNK 8192
#define MAXBK 512  // supports N <= 131072

// --- phase A: count bucket sizes (per-block LDS hist -> global atomics) ---
__global__ __launch_bounds__(256) void countb_k(const int* __restrict__ eidx,
                                                uint32* __restrict__ bkt_size, int E) {
    __shared__ uint32 hist[MAXBK];
    int t = threadIdx.x;
    hist[t] = 0; hist[t + 256] = 0;
    __syncthreads();
    int base = blockIdx.x * CHUNK;
    int n = E - base; if (n > CHUNK) n = CHUNK;
    for (int i = t; i < n; i += 256) {
        int d = eidx[E + base + i];
        atomicAdd(&hist[d >> 8], 1u);
    }
    __syncthreads();
    uint32 c0 = hist[t], c1 = hist[t + 256];
    if (c0) atomicAdd(&bkt_size[t], c0);
    if (c1) atomicAdd(&bkt_size[t + 256], c1);
}

// --- phase B: exclusive scan of bucket sizes -> bkt_base, bkt_cur ---
__global__ __launch_bounds__(MAXBK) void scanb_k(const uint32* __restrict__ bkt_size,
                                                 uint32* __restrict__ bkt_base,
                                                 uint32* __restrict__ bkt_cur, int nbk) {
    __shared__ uint32 s[MAXBK];
    int t = threadIdx.x;
    uint32 v = (t < nbk) ? bkt_size[t] : 0;
    s[t] = v;
    __syncthreads();
    for (int off = 1; off < MAXBK; off <<= 1) {
        uint32 x = (t >= off) ? s[t - off] : 0;
        __syncthreads();
        s[t] += x;
        __syncthreads();
    }
    uint32 excl = s[t] - v;
    bkt_base[t] = excl;
    bkt_cur[t] = excl;
}

// --- phase C: scatter edges into bucket segments (LDS-staged, coalesced) ---
__global__ __launch_bounds__(256) void scatterb_k(const int* __restrict__ eidx,
                                                  uint32* __restrict__ bkt_cur,
                                                  uint32* __restrict__ packed, int E) {
    __shared__ uint32 hist[MAXBK];
    __shared__ uint32 temp[256];
    __shared__ uint32 hsc[MAXBK + 1];
    __shared__ uint32 gbase[MAXBK];
    __shared__ uint32 lcur[MAXBK];
    __shared__ uint32 stage[CHUNK];
    int t = threadIdx.x;
    int cbase = blockIdx.x * CHUNK;
    int n = E - cbase; if (n > CHUNK) n = CHUNK;

    hist[t] = 0; hist[t + 256] = 0;
    __syncthreads();
    for (int i = t; i < n; i += 256) {
        int d = eidx[E + cbase + i];
        atomicAdd(&hist[d >> 8], 1u);
    }
    __syncthreads();
    // pair-based exclusive scan of hist[512] -> hsc[513]
    uint32 c0 = hist[2 * t], c1 = hist[2 * t + 1];
    temp[t] = c0 + c1;
    __syncthreads();
    for (int off = 1; off < 256; off <<= 1) {
        uint32 x = (t >= off) ? temp[t - off] : 0;
        __syncthreads();
        temp[t] += x;
        __syncthreads();
    }
    uint32 exclp = temp[t] - (c0 + c1);
    hsc[2 * t] = exclp;
    hsc[2 * t + 1] = exclp + c0;
    if (t == 255) hsc[MAXBK] = temp[255];
    // reserve global segments + init local cursors
    lcur[2 * t] = exclp;
    lcur[2 * t + 1] = exclp + c0;
    if (c0) gbase[2 * t] = atomicAdd(&bkt_cur[2 * t], c0);
    if (c1) gbase[2 * t + 1] = atomicAdd(&bkt_cur[2 * t + 1], c1);
    __syncthreads();
    // place packed edges into LDS stage, bucket-grouped
    for (int i = t; i < n; i += 256) {
        int s = eidx[cbase + i];
        int d = eidx[E + cbase + i];
        int b = d >> 8;
        uint32 pos = atomicAdd(&lcur[b], 1u);
        stage[pos] = ((uint32)s << 8) | (uint32)(d & 255);
    }
    __syncthreads();
    // write out: consecutive threads -> consecutive addresses within segment
    for (int i = t; i < n; i += 256) {
        // largest b with hsc[b] <= i
        int lo = 0, hi = MAXBK - 1;
        while (lo < hi) {
            int mid = (lo + hi + 1) >> 1;
            if (hsc[mid] <= (uint32)i) lo = mid; else hi = mid - 1;
        }
        packed[gbase[lo] + (i - hsc[lo])] = stage[i];
    }
}

// --- phase D: per-bucket CSR finalize + degrees + rowp + dinv ---
__global__ __launch_bounds__(256) void buildb_k(const uint32* __restrict__ packed,
                                                const uint32* __restrict__ bkt_base,
                                                const uint32* __restrict__ bkt_size,
                                                int* __restrict__ rowp,
                                                float* __restrict__ dinv,
                                                int* __restrict__ csr, int N, int E) {
    __shared__ uint32 cnt[256];
    __shared__ uint32 incl[256];
    __shared__ uint32 cur[256];
    int t = threadIdx.x;
    int b = blockIdx.x;
    uint32 base = bkt_base[b];
    uint32 size = bkt_size[b];
    int node0 = b << 8;

    cnt[t] = 0;
    __syncthreads();
    for (uint32 i = t; i < size; i += 256)
        atomicAdd(&cnt[packed[base + i] & 255u], 1u);
    __syncthreads();
    uint32 v = cnt[t];
    incl[t] = v;
    __syncthreads();
    for (int off = 1; off < 256; off <<= 1) {
        uint32 x = (t >= off) ? incl[t - off] : 0;
        __syncthreads();
        incl[t] += x;
        __syncthreads();
    }
    uint32 loc = incl[t] - v;  // exclusive
    cur[t] = loc;
    int node = node0 + t;
    if (node < N) {
        dinv[node] = rsqrtf((float)v + 2.0f);
        rowp[node] = (int)(base + loc);
        if (node == N - 1) rowp[N] = E;
    }
    __syncthreads();
    for (uint32 i = t; i < size; i += 256) {
        uint32 p = packed[base + i];
        uint32 pos = atomicAdd(&cur[p & 255u], 1u);
        csr[base + pos] = (int)(p >> 8);
    }
}

// ------- weight prep (all 6 at once): W fp32 [128][128] -> Wt_hi/Wt_lo bf16 (transposed)

__global__ __launch_bounds__(256) void prep_w6_k(const float* __restrict__ w0,
                                                 const float* __restrict__ w1,
                                                 const float* __restrict__ w2,
                                                 const float* __restrict__ w3,
                                                 const float* __restrict__ w4,
                                                 const float* __restrict__ w5,
                                                 unsigned short* __restrict__ Wt_hi,
                                                 unsigned short* __restrict__ Wt_lo) {
    int widx = blockIdx.x >> 6;  // 64 blocks per weight
    const float* W;
    switch (widx) {
        case 0: W = w0; break;
        case 1: W = w1; break;
        case 2: W = w2; break;
        case 3: W = w3; break;
        case 4: W = w4; break;
        default: W = w5; break;
    }
    int t = (blockIdx.x & 63) * 256 + threadIdx.x;
    int c = t & 127, k = t >> 7;
    float w = W[k * 128 + c];
    unsigned short hi = f2b(w);
    float lo = w - b2f(hi);
    Wt_hi[widx * 16384 + c * 128 + k] = hi;
    Wt_lo[widx * 16384 + c * 128 + k] = f2b(lo);
}

// ---------------- GEMM v2: 64 rows/block, 4 waves x 16 rows, 64 MFMA/wave ----------
// ASRC 0: A is fp32 (convert to bf16 in-flight)    ASRC 1: A is bf16 storage
// MODE 0: out = dinv[i] * (A @ W)   (z for conv)   MODE 1: out = tanh(A @ W + bias)

template <int ASRC, int MODE>
__global__ __launch_bounds__(256) void gemm128_k(
    const void* __restrict__ Asrc,
    const unsigned short* __restrict__ Wt_hi,
    const unsigned short* __restrict__ Wt_lo,
    const float* __restrict__ dinv, const float* __restrict__ bias,
    unsigned short* __restrict__ out, int N) {
    int tid = threadIdx.x;
    int wave = tid >> 6, lane = tid & 63;
    int quad = lane >> 4, r = lane & 15;
    int m16 = blockIdx.x * 64 + wave * 16;  // this wave's 16-row tile

    int rowA = m16 + r;
    if (rowA >= N) rowA = N - 1;  // clamp (stores guarded below)

    short8 afrag[4];
    if (ASRC == 0) {
        const float* Af = (const float*)Asrc;
#pragma unroll
        for (int kc = 0; kc < 4; ++kc) {
            const float* p = Af + (size_t)rowA * 128 + kc * 32 + quad * 8;
            short8 a;
#pragma unroll
            for (int j = 0; j < 8; ++j) a[j] = (short)f2b(p[j]);
            afrag[kc] = a;
        }
    } else {
        const short* Ap = (const short*)Asrc;
#pragma unroll
        for (int kc = 0; kc < 4; ++kc)
            afrag[kc] = *(const short8*)(Ap + (size_t)rowA * 128 + kc * 32 + quad * 8);
    }

    // hoist per-row dinv (MODE 0): rows m16 + quad*4 + reg
    float dv[4];
    if (MODE == 0) {
#pragma unroll
        for (int reg = 0; reg < 4; ++reg) {
            int i = m16 + quad * 4 + reg;
            dv[reg] = dinv[i < N ? i : N - 1];
        }
    }

    const short* Wh = (const short*)Wt_hi;
    const short* Wl = (const short*)Wt_lo;

#pragma unroll
    for (int ct = 0; ct < 8; ++ct) {
        int n = ct * 16 + r;  // output column this lane covers
        floatx4 acc = {0.f, 0.f, 0.f, 0.f};
#pragma unroll
        for (int kc = 0; kc < 4; ++kc) {
            short8 bh8 = *(const short8*)(Wh + n * 128 + kc * 32 + quad * 8);
            acc = __builtin_amdgcn_mfma_f32_16x16x32_bf16(afrag[kc], bh8, acc, 0, 0, 0);
            short8 bl8 = *(const short8*)(Wl + n * 128 + kc * 32 + quad * 8);
            acc = __builtin_amdgcn_mfma_f32_16x16x32_bf16(afrag[kc], bl8, acc, 0, 0, 0);
        }
        float bv = (MODE == 1) ? bias[n] : 0.f;
#pragma unroll
        for (int reg = 0; reg < 4; ++reg) {
            int i = m16 + quad * 4 + reg;  // D: row = quad*4+reg
            if (i < N) {
                float v = acc[reg];
                if (MODE == 0) v *= dv[reg];
                else v = tanhf(v + bv);
                out[(size_t)i * 128 + n] = f2b(v);
            }
        }
    }
}

// ---------------- Aggregation: h[i] = tanh(dinv_i*(sum_e z[src_e] + 2 z_i) + b) --------
// One wave per node. Lanes 0-31 process even edges, lanes 32-63 odd edges;
// each lane covers 4 channels (uint2 = 8B). Chunks of 16 edges issue 8
// independent dwordx2 loads before any accumulate -> ~8 loads in flight/wave.

__global__ __launch_bounds__(256) void agg_tanh_k(
    const uint32* __restrict__ z, const int* __restrict__ rowp,
    const int* __restrict__ csr, const float* __restrict__ dinv,
    const float* __restrict__ bias, uint32* __restrict__ out, int N) {
    int lane = threadIdx.x & 63;
    int half = lane >> 5;   // 0: even edges, 1: odd edges
    int c4 = lane & 31;     // 4-channel group (channels 4*c4 .. 4*c4+3)
    int i = blockIdx.x * 4 + (threadIdx.x >> 6);
    if (i >= N) return;
    int start = rowp[i], end = rowp[i + 1];
    const uintx2* z2 = (const uintx2*)z;
    float a0 = 0.f, a1 = 0.f, a2 = 0.f, a3 = 0.f;
    for (int e = start; e < end; e += 64) {
        int cnt = end - e;
        if (cnt > 64) cnt = 64;
        int s = (lane < cnt) ? csr[e + lane] : 0;
        for (int m = 0; m < cnt; m += 16) {
            uintx2 v[8];
            float f[8];
#pragma unroll
            for (int p = 0; p < 8; ++p) {
                int idx = m + 2 * p + half;
                int sj = __shfl(s, idx);            // per-lane bpermute
                f[p] = (idx < cnt) ? 1.f : 0.f;
                v[p] = z2[(size_t)sj * 32 + c4];    // 8 loads in flight
            }
#pragma unroll
            for (int p = 0; p < 8; ++p) {
                a0 = fmaf(bl(v[p][0]), f[p], a0);
                a1 = fmaf(bh(v[p][0]), f[p], a1);
                a2 = fmaf(bl(v[p][1]), f[p], a2);
                a3 = fmaf(bh(v[p][1]), f[p], a3);
            }
        }
    }
    // combine even/odd halves (channels match across half-waves)
    a0 += __shfl_xor(a0, 32);
    a1 += __shfl_xor(a1, 32);
    a2 += __shfl_xor(a2, 32);
    a3 += __shfl_xor(a3, 32);
    if (half == 0) {
        uintx2 vi = z2[(size_t)i * 32 + c4];
        a0 += 2.f * bl(vi[0]);
        a1 += 2.f * bh(vi[0]);
        a2 += 2.f * bl(vi[1]);
        a3 += 2.f * bh(vi[1]);
        float di = dinv[i];
        float4 bv = ((const float4*)bias)[c4];
        float h0 = tanhf(fmaf(di, a0, bv.x));
        float h1 = tanhf(fmaf(di, a1, bv.y));
        float h2 = tanhf(fmaf(di, a2, bv.z));
        float h3 = tanhf(fmaf(di, a3, bv.w));
        uintx2 o;
        o[0] = (uint32)f2b(h0) | ((uint32)f2b(h1) << 16);
        o[1] = (uint32)f2b(h2) | ((uint32)f2b(h3) << 16);
        ((uintx2*)out)[(size_t)i * 32 + c4] = o;
    }
}

// ---------------- Final layer: out[N,3] = H @ lw4 + lb4 (fp32 out) ----------------

__global__ __launch_bounds__(256) void final_k(const unsigned short* __restrict__ H,
                                               const float* __restrict__ W4,
                                               const float* __restrict__ b4,
                                               float* __restrict__ out, int N) {
    __shared__ float wsm[128][3];
    int tid = threadIdx.x;
    if (tid < 128) {
#pragma unroll
        for (int c = 0; c < 3; ++c) wsm[tid][c] = W4[tid * 3 + c];
    }
    __syncthreads();
    int i = blockIdx.x * 256 + tid;
    if (i >= N) return;
    const uint32* hp = (const uint32*)(H + (size_t)i * 128);
    float acc0 = b4[0], acc1 = b4[1], acc2 = b4[2];
    for (int w = 0; w < 64; ++w) {
        uint32 v = hp[w];
        float x0 = bl(v), x1 = bh(v);
        acc0 += x0 * wsm[2 * w][0] + x1 * wsm[2 * w + 1][0];
        acc1 += x0 * wsm[2 * w][1] + x1 * wsm[2 * w + 1][1];
        acc2 += x0 * wsm[2 * w][2] + x1 * wsm[2 * w + 1][2];
    }
    out[(size_t)i * 3 + 0] = acc0;
    out[(size_t)i * 3 + 1] = acc1;
    out[(size_t)i * 3 + 2] = acc2;
}

extern "C" void kernel_launch(void* const* d_in, const int* in_sizes, int n_in,
                              void* d_out, int out_size, void* d_ws, size_t ws_size,
                              hipStream_t stream) {
    const float* x   = (const float*)d_in[0];
    const int* eidx  = (const int*)d_in[1];
    const float* W1  = (const float*)d_in[2];
    const float* b1  = (const float*)d_in[3];
    const float* W2  = (const float*)d_in[4];
    const float* b2  = (const float*)d_in[5];
    const float* lw1 = (const float*)d_in[6];
    const float* lb1 = (const float*)d_in[7];
    const float* lw2 = (const float*)d_in[8];
    const float* lb2 = (const float*)d_in[9];
    const float* lw3 = (const float*)d_in[10];
    const float* lb3 = (const float*)d_in[11];
    const float* lw4 = (const float*)d_in[12];
    const float* lb4 = (const float*)d_in[13];
    float* out = (float*)d_out;

    const int N = in_sizes[0] / 128;
    const int E = in_sizes[1] / 2;

    // workspace carve (256B aligned); total ~65.3 MB
    char* p = (char*)d_ws;
    auto alloc = [&](size_t bytes) -> void* {
        void* q = (void*)p;
        p += (bytes + 255) & ~(size_t)255;
        return q;
    };
    float* dinv      = (float*)alloc((size_t)N * 4);
    int* rowp        = (int*)alloc((size_t)(N + 1) * 4);
    uint32* bkt_size = (uint32*)alloc(MAXBK * 4);
    uint32* bkt_base = (uint32*)alloc(MAXBK * 4);
    uint32* bkt_cur  = (uint32*)alloc(MAXBK * 4);
    int* csr         = (int*)alloc((size_t)E * 4);
    unsigned short* Wt_hi = (unsigned short*)alloc(6 * 16384 * 2);
    unsigned short* Wt_lo = (unsigned short*)alloc(6 * 16384 * 2);
    unsigned short* bufA  = (unsigned short*)alloc((size_t)N * 128 * 2);
    unsigned short* bufB  = (unsigned short*)alloc((size_t)N * 128 * 2);
    uint32* packed = (uint32*)bufA;  // alias: packed (E*4 B) dead before gemm1 writes bufA

    const int NB  = (N + 255) / 256;
    const int MB  = (N + 63) / 64;
    const int AB  = (N + 3) / 4;
    const int NCH = (E + CHUNK - 1) / CHUNK;
    const int NBK = (N + 255) >> 8;  // must be <= MAXBK

    // CSR build (bucket sort) + weight prep
    hipMemsetAsync(bkt_size, 0, MAXBK * 4, stream);
    countb_k<<<NCH, 256, 0, stream>>>(eidx, bkt_size, E);
    prep_w6_k<<<384, 256, 0, stream>>>(W1, W2, lw1, lw2, lw3, lw4, Wt_hi, Wt_lo);
    scanb_k<<<1, MAXBK, 0, stream>>>(bkt_size, bkt_base, bkt_cur, NBK);
    scatterb_k<<<NCH, 256, 0, stream>>>(eidx, bkt_cur, packed, E);
    buildb_k<<<NBK, 256, 0, stream>>>(packed, bkt_base, bkt_size, rowp, dinv, csr, N, E);

    const unsigned short* WH = Wt_hi;
    const unsigned short* WL = Wt_lo;

    // conv1: z1 = dinv * (x @ W1) ; h1 = tanh(dinv*(sum z1 + 2 z1_i) + b1)
    gemm128_k<0, 0><<<MB, 256, 0, stream>>>(x, WH + 0 * 16384, WL + 0 * 16384,
                                            dinv, nullptr, bufA, N);
    agg_tanh_k<<<AB, 256, 0, stream>>>((const uint32*)bufA, rowp, csr, dinv, b1,
                                       (uint32*)bufB, N);
    // conv2
    gemm128_k<1, 0><<<MB, 256, 0, stream>>>(bufB, WH + 1 * 16384, WL + 1 * 16384,
                                            dinv, nullptr, bufA, N);
    agg_tanh_k<<<AB, 256, 0, stream>>>((const uint32*)bufA, rowp, csr, dinv, b2,
                                       (uint32*)bufB, N);
    // MLP
    gemm128_k<1, 1><<<MB, 256, 0, stream>>>(bufB, WH + 2 * 16384, WL + 2 * 16384,
                                            nullptr, lb1, bufA, N);
    gemm128_k<1, 1><<<MB, 256, 0, stream>>>(bufA, WH + 3 * 16384, WL + 3 * 16384,
                                            nullptr, lb2, bufB, N);
    gemm128_k<1, 1><<<MB, 256, 0, stream>>>(bufB, WH + 4 * 16384, WL + 4 * 16384,
                                            nullptr, lb3, bufA, N);
    final_k<<<NB, 256, 0, stream>>>(bufA, lw4, lb4, out, N);
}

// Round 6
// 674.209 us; speedup vs baseline: 1.8275x; 1.0621x over previous
//
#include <hip/hip_runtime.h>

typedef __attribute__((ext_vector_type(8))) short short8;
typedef __attribute__((ext_vector_type(4))) float floatx4;
typedef __attribute__((ext_vector_type(2))) unsigned int uintx2;
typedef unsigned int uint32;

__device__ inline float b2f(unsigned short u) {
    union { uint32 i; float f; } x; x.i = ((uint32)u) << 16; return x.f;
}
__device__ inline float bl(uint32 v) {
    union { uint32 i; float f; } x; x.i = v << 16; return x.f;
}
__device__ inline float bh(uint32 v) {
    union { uint32 i; float f; } x; x.i = v & 0xffff0000u; return x.f;
}
__device__ inline unsigned short f2b(float f) {
    union { float f; uint32 u; } x; x.f = f;
    uint32 r = x.u + 0x7fffu + ((x.u >> 16) & 1u);
    return (unsigned short)(r >> 16);
}

// ================= CSR build via 2-level bucket sort =================
// bucket b owns nodes [b*256, b*256+255]; csr layout is bucket-major ==
// dst-major, so bucket bases double as csr row-pointer bases.
// packed edge word: (src << 8) | (dst & 255)   (requires N < 2^24)

#define CHUNK 8192
#define MAXBK 512  // supports N <= 131072

__global__ __launch_bounds__(256) void countb_k(const int* __restrict__ eidx,
                                                uint32* __restrict__ bkt_size, int E) {
    __shared__ uint32 hist[MAXBK];
    int t = threadIdx.x;
    hist[t] = 0; hist[t + 256] = 0;
    __syncthreads();
    int base = blockIdx.x * CHUNK;
    int n = E - base; if (n > CHUNK) n = CHUNK;
    for (int i = t; i < n; i += 256) {
        int d = eidx[E + base + i];
        atomicAdd(&hist[d >> 8], 1u);
    }
    __syncthreads();
    uint32 c0 = hist[t], c1 = hist[t + 256];
    if (c0) atomicAdd(&bkt_size[t], c0);
    if (c1) atomicAdd(&bkt_size[t + 256], c1);
}

__global__ __launch_bounds__(MAXBK) void scanb_k(const uint32* __restrict__ bkt_size,
                                                 uint32* __restrict__ bkt_base,
                                                 uint32* __restrict__ bkt_cur, int nbk) {
    __shared__ uint32 s[MAXBK];
    int t = threadIdx.x;
    uint32 v = (t < nbk) ? bkt_size[t] : 0;
    s[t] = v;
    __syncthreads();
    for (int off = 1; off < MAXBK; off <<= 1) {
        uint32 x = (t >= off) ? s[t - off] : 0;
        __syncthreads();
        s[t] += x;
        __syncthreads();
    }
    uint32 excl = s[t] - v;
    bkt_base[t] = excl;
    bkt_cur[t] = excl;
}

__global__ __launch_bounds__(256) void scatterb_k(const int* __restrict__ eidx,
                                                  uint32* __restrict__ bkt_cur,
                                                  uint32* __restrict__ packed, int E) {
    __shared__ uint32 hist[MAXBK];
    __shared__ uint32 temp[256];
    __shared__ uint32 hsc[MAXBK + 1];
    __shared__ uint32 gbase[MAXBK];
    __shared__ uint32 lcur[MAXBK];
    __shared__ uint32 stage[CHUNK];
    int t = threadIdx.x;
    int cbase = blockIdx.x * CHUNK;
    int n = E - cbase; if (n > CHUNK) n = CHUNK;

    hist[t] = 0; hist[t + 256] = 0;
    __syncthreads();
    for (int i = t; i < n; i += 256) {
        int d = eidx[E + cbase + i];
        atomicAdd(&hist[d >> 8], 1u);
    }
    __syncthreads();
    uint32 c0 = hist[2 * t], c1 = hist[2 * t + 1];
    temp[t] = c0 + c1;
    __syncthreads();
    for (int off = 1; off < 256; off <<= 1) {
        uint32 x = (t >= off) ? temp[t - off] : 0;
        __syncthreads();
        temp[t] += x;
        __syncthreads();
    }
    uint32 exclp = temp[t] - (c0 + c1);
    hsc[2 * t] = exclp;
    hsc[2 * t + 1] = exclp + c0;
    if (t == 255) hsc[MAXBK] = temp[255];
    lcur[2 * t] = exclp;
    lcur[2 * t + 1] = exclp + c0;
    if (c0) gbase[2 * t] = atomicAdd(&bkt_cur[2 * t], c0);
    if (c1) gbase[2 * t + 1] = atomicAdd(&bkt_cur[2 * t + 1], c1);
    __syncthreads();
    for (int i = t; i < n; i += 256) {
        int s = eidx[cbase + i];
        int d = eidx[E + cbase + i];
        int b = d >> 8;
        uint32 pos = atomicAdd(&lcur[b], 1u);
        stage[pos] = ((uint32)s << 8) | (uint32)(d & 255);
    }
    __syncthreads();
    for (int i = t; i < n; i += 256) {
        int lo = 0, hi = MAXBK - 1;
        while (lo < hi) {
            int mid = (lo + hi + 1) >> 1;
            if (hsc[mid] <= (uint32)i) lo = mid; else hi = mid - 1;
        }
        packed[gbase[lo] + (i - hsc[lo])] = stage[i];
    }
}

__global__ __launch_bounds__(256) void buildb_k(const uint32* __restrict__ packed,
                                                const uint32* __restrict__ bkt_base,
                                                const uint32* __restrict__ bkt_size,
                                                int* __restrict__ rowp,
                                                float* __restrict__ dinv,
                                                int* __restrict__ csr, int N, int E) {
    __shared__ uint32 cnt[256];
    __shared__ uint32 incl[256];
    __shared__ uint32 cur[256];
    int t = threadIdx.x;
    int b = blockIdx.x;
    uint32 base = bkt_base[b];
    uint32 size = bkt_size[b];
    int node0 = b << 8;

    cnt[t] = 0;
    __syncthreads();
    for (uint32 i = t; i < size; i += 256)
        atomicAdd(&cnt[packed[base + i] & 255u], 1u);
    __syncthreads();
    uint32 v = cnt[t];
    incl[t] = v;
    __syncthreads();
    for (int off = 1; off < 256; off <<= 1) {
        uint32 x = (t >= off) ? incl[t - off] : 0;
        __syncthreads();
        incl[t] += x;
        __syncthreads();
    }
    uint32 loc = incl[t] - v;  // exclusive
    cur[t] = loc;
    int node = node0 + t;
    if (node < N) {
        dinv[node] = rsqrtf((float)v + 2.0f);
        rowp[node] = (int)(base + loc);
        if (node == N - 1) rowp[N] = E;
    }
    __syncthreads();
    for (uint32 i = t; i < size; i += 256) {
        uint32 p = packed[base + i];
        uint32 pos = atomicAdd(&cur[p & 255u], 1u);
        csr[base + pos] = (int)(p >> 8);
    }
}

// ------- weight prep (all 6 at once): W fp32 [128][128] -> Wt_hi/Wt_lo bf16 (transposed)

__global__ __launch_bounds__(256) void prep_w6_k(const float* __restrict__ w0,
                                                 const float* __restrict__ w1,
                                                 const float* __restrict__ w2,
                                                 const float* __restrict__ w3,
                                                 const float* __restrict__ w4,
                                                 unsigned short* __restrict__ Wt_hi,
                                                 unsigned short* __restrict__ Wt_lo) {
    int widx = blockIdx.x >> 6;  // 64 blocks per weight
    const float* W;
    switch (widx) {
        case 0: W = w0; break;
        case 1: W = w1; break;
        case 2: W = w2; break;
        case 3: W = w3; break;
        default: W = w4; break;
    }
    int t = (blockIdx.x & 63) * 256 + threadIdx.x;
    int c = t & 127, k = t >> 7;
    float w = W[k * 128 + c];
    unsigned short hi = f2b(w);
    float lo = w - b2f(hi);
    Wt_hi[widx * 16384 + c * 128 + k] = hi;
    Wt_lo[widx * 16384 + c * 128 + k] = f2b(lo);
}

// ---------------- conv GEMM: z = dinv * (A @ W), 128 rows/block, 32 rows/wave --------
// ASRC 0: A fp32;  ASRC 1: A bf16 storage.

template <int ASRC>
__global__ __launch_bounds__(256) void gemm_z_k(
    const void* __restrict__ Asrc,
    const unsigned short* __restrict__ Wt_hi,
    const unsigned short* __restrict__ Wt_lo,
    const float* __restrict__ dinv,
    unsigned short* __restrict__ out, int N) {
    int tid = threadIdx.x;
    int wave = tid >> 6, lane = tid & 63;
    int quad = lane >> 4, r = lane & 15;
    int m32 = blockIdx.x * 128 + wave * 32;

    short8 af[2][4];
#pragma unroll
    for (int s = 0; s < 2; ++s) {
        int rowA = m32 + s * 16 + r;
        if (rowA >= N) rowA = N - 1;
        if (ASRC == 0) {
            const float4* Af = (const float4*)Asrc;
#pragma unroll
            for (int kc = 0; kc < 4; ++kc) {
                float4 p0 = Af[((size_t)rowA * 128 + kc * 32 + quad * 8) >> 2];
                float4 p1 = Af[(((size_t)rowA * 128 + kc * 32 + quad * 8) >> 2) + 1];
                short8 a;
                a[0] = (short)f2b(p0.x); a[1] = (short)f2b(p0.y);
                a[2] = (short)f2b(p0.z); a[3] = (short)f2b(p0.w);
                a[4] = (short)f2b(p1.x); a[5] = (short)f2b(p1.y);
                a[6] = (short)f2b(p1.z); a[7] = (short)f2b(p1.w);
                af[s][kc] = a;
            }
        } else {
            const short* Ap = (const short*)Asrc;
#pragma unroll
            for (int kc = 0; kc < 4; ++kc)
                af[s][kc] = *(const short8*)(Ap + (size_t)rowA * 128 + kc * 32 + quad * 8);
        }
    }

    float dv[2][4];
#pragma unroll
    for (int s = 0; s < 2; ++s)
#pragma unroll
        for (int reg = 0; reg < 4; ++reg) {
            int i = m32 + s * 16 + quad * 4 + reg;
            dv[s][reg] = dinv[i < N ? i : N - 1];
        }

    const short* Wh = (const short*)Wt_hi;
    const short* Wl = (const short*)Wt_lo;

#pragma unroll
    for (int ct = 0; ct < 8; ++ct) {
        int n = ct * 16 + r;
        floatx4 a0 = {0.f, 0.f, 0.f, 0.f}, a1 = {0.f, 0.f, 0.f, 0.f};
#pragma unroll
        for (int kc = 0; kc < 4; ++kc) {
            short8 bh8 = *(const short8*)(Wh + n * 128 + kc * 32 + quad * 8);
            a0 = __builtin_amdgcn_mfma_f32_16x16x32_bf16(af[0][kc], bh8, a0, 0, 0, 0);
            a1 = __builtin_amdgcn_mfma_f32_16x16x32_bf16(af[1][kc], bh8, a1, 0, 0, 0);
            short8 bl8 = *(const short8*)(Wl + n * 128 + kc * 32 + quad * 8);
            a0 = __builtin_amdgcn_mfma_f32_16x16x32_bf16(af[0][kc], bl8, a0, 0, 0, 0);
            a1 = __builtin_amdgcn_mfma_f32_16x16x32_bf16(af[1][kc], bl8, a1, 0, 0, 0);
        }
#pragma unroll
        for (int reg = 0; reg < 4; ++reg) {
            int i0 = m32 + quad * 4 + reg;
            if (i0 < N) out[(size_t)i0 * 128 + n] = f2b(a0[reg] * dv[0][reg]);
            int i1 = m32 + 16 + quad * 4 + reg;
            if (i1 < N) out[(size_t)i1 * 128 + n] = f2b(a1[reg] * dv[1][reg]);
        }
    }
}

// ---------------- fused MLP head: h2 -> tanh^3 chain -> [N,3] fp32 ----------------
// 128 rows/block, 32 rows/wave. Per-wave LDS tile round-trips C-layout -> A-layout
// between layers (no barriers: each wave consumes only its own tile).

#define LSTR 136  // LDS row stride in shorts (128 + 8 pad)

__global__ __launch_bounds__(256) void mlp_fused_k(
    const unsigned short* __restrict__ H,
    const unsigned short* __restrict__ WH,   // lw1,lw2,lw3 hi at L*16384
    const unsigned short* __restrict__ WL,
    const float* __restrict__ lb1, const float* __restrict__ lb2,
    const float* __restrict__ lb3,
    const float* __restrict__ W4, const float* __restrict__ b4,
    float* __restrict__ out, int N) {
    __shared__ unsigned short tile[4][32 * LSTR];
    __shared__ float w4s[384];
    int tid = threadIdx.x;
    if (tid < 192) { w4s[tid] = W4[tid]; w4s[tid + 192] = W4[tid + 192]; }
    __syncthreads();

    int wave = tid >> 6, lane = tid & 63;
    int quad = lane >> 4, r = lane & 15;
    unsigned short* T = tile[wave];
    int m32 = blockIdx.x * 128 + wave * 32;

    short8 af[2][4];
    const short* Hp = (const short*)H;
#pragma unroll
    for (int s = 0; s < 2; ++s) {
        int rowA = m32 + s * 16 + r;
        if (rowA >= N) rowA = N - 1;
#pragma unroll
        for (int kc = 0; kc < 4; ++kc)
            af[s][kc] = *(const short8*)(Hp + (size_t)rowA * 128 + kc * 32 + quad * 8);
    }

    const float* biases[3] = {lb1, lb2, lb3};
#pragma unroll
    for (int L = 0; L < 3; ++L) {
        const short* Wh = (const short*)WH + L * 16384;
        const short* Wl = (const short*)WL + L * 16384;
        const float* bias = biases[L];
#pragma unroll
        for (int ct = 0; ct < 8; ++ct) {
            int n = ct * 16 + r;
            floatx4 a0 = {0.f, 0.f, 0.f, 0.f}, a1 = {0.f, 0.f, 0.f, 0.f};
#pragma unroll
            for (int kc = 0; kc < 4; ++kc) {
                short8 bh8 = *(const short8*)(Wh + n * 128 + kc * 32 + quad * 8);
                a0 = __builtin_amdgcn_mfma_f32_16x16x32_bf16(af[0][kc], bh8, a0, 0, 0, 0);
                a1 = __builtin_amdgcn_mfma_f32_16x16x32_bf16(af[1][kc], bh8, a1, 0, 0, 0);
                short8 bl8 = *(const short8*)(Wl + n * 128 + kc * 32 + quad * 8);
                a0 = __builtin_amdgcn_mfma_f32_16x16x32_bf16(af[0][kc], bl8, a0, 0, 0, 0);
                a1 = __builtin_amdgcn_mfma_f32_16x16x32_bf16(af[1][kc], bl8, a1, 0, 0, 0);
            }
            float bv = bias[n];
#pragma unroll
            for (int reg = 0; reg < 4; ++reg) {
                int lrow = quad * 4 + reg;
                T[lrow * LSTR + n] = f2b(tanhf(a0[reg] + bv));
                T[(lrow + 16) * LSTR + n] = f2b(tanhf(a1[reg] + bv));
            }
        }
        // C-layout tile -> A-fragments for next layer (same wave; lgkmcnt only)
        if (L < 2) {
#pragma unroll
            for (int s = 0; s < 2; ++s)
#pragma unroll
                for (int kc = 0; kc < 4; ++kc)
                    af[s][kc] = *(const short8*)&T[(s * 16 + r) * LSTR + kc * 32 + quad * 8];
        }
    }

    // layer 4: lane handles row (lane&31), channel half (lane>>5)
    int lrow = lane & 31;
    int halfc = lane >> 5;
    float a0 = 0.f, a1 = 0.f, a2 = 0.f;
#pragma unroll
    for (int c8 = 0; c8 < 8; ++c8) {
        int cbase = halfc * 64 + c8 * 8;
        short8 hv = *(const short8*)&T[lrow * LSTR + cbase];
#pragma unroll
        for (int j = 0; j < 8; ++j) {
            float xv = b2f((unsigned short)hv[j]);
            int ch = cbase + j;
            a0 = fmaf(xv, w4s[ch * 3 + 0], a0);
            a1 = fmaf(xv, w4s[ch * 3 + 1], a1);
            a2 = fmaf(xv, w4s[ch * 3 + 2], a2);
        }
    }
    a0 += __shfl_xor(a0, 32);
    a1 += __shfl_xor(a1, 32);
    a2 += __shfl_xor(a2, 32);
    if (halfc == 0) {
        int i = m32 + lrow;
        if (i < N) {
            out[(size_t)i * 3 + 0] = a0 + b4[0];
            out[(size_t)i * 3 + 1] = a1 + b4[1];
            out[(size_t)i * 3 + 2] = a2 + b4[2];
        }
    }
}

// ---------------- Aggregation: h[i] = tanh(dinv_i*(sum_e z[src_e] + 2 z_i) + b) --------
// One wave per node; lanes 0-31 even edges, 32-63 odd; 4 channels (8B) per lane.
// Pad lanes use src = N -> zeroed z row (no per-edge masking VALU).

__global__ __launch_bounds__(256) void agg_tanh_k(
    const uint32* __restrict__ z, const int* __restrict__ rowp,
    const int* __restrict__ csr, const float* __restrict__ dinv,
    const float* __restrict__ bias, uint32* __restrict__ out, int N) {
    int lane = threadIdx.x & 63;
    int half = lane >> 5;
    int c4 = lane & 31;
    int i = blockIdx.x * 4 + (threadIdx.x >> 6);
    if (i >= N) return;
    int start = rowp[i], end = rowp[i + 1];
    const uintx2* z2 = (const uintx2*)z;
    float a0 = 0.f, a1 = 0.f, a2 = 0.f, a3 = 0.f;
    for (int e = start; e < end; e += 64) {
        int cnt = end - e;
        if (cnt > 64) cnt = 64;
        int s = (lane < cnt) ? csr[e + lane] : N;  // N = zero row
        int mp = (cnt + 15) & ~15;
        for (int m = 0; m < mp; m += 16) {
            uintx2 v[8];
#pragma unroll
            for (int p = 0; p < 8; ++p) {
                int sj = __shfl(s, m + 2 * p + half);
                v[p] = z2[(size_t)sj * 32 + c4];
            }
#pragma unroll
            for (int p = 0; p < 8; ++p) {
                a0 += bl(v[p][0]);
                a1 += bh(v[p][0]);
                a2 += bl(v[p][1]);
                a3 += bh(v[p][1]);
            }
        }
    }
    a0 += __shfl_xor(a0, 32);
    a1 += __shfl_xor(a1, 32);
    a2 += __shfl_xor(a2, 32);
    a3 += __shfl_xor(a3, 32);
    if (half == 0) {
        uintx2 vi = z2[(size_t)i * 32 + c4];
        a0 += 2.f * bl(vi[0]);
        a1 += 2.f * bh(vi[0]);
        a2 += 2.f * bl(vi[1]);
        a3 += 2.f * bh(vi[1]);
        float di = dinv[i];
        float4 bv = ((const float4*)bias)[c4];
        float h0 = tanhf(fmaf(di, a0, bv.x));
        float h1 = tanhf(fmaf(di, a1, bv.y));
        float h2 = tanhf(fmaf(di, a2, bv.z));
        float h3 = tanhf(fmaf(di, a3, bv.w));
        uintx2 o;
        o[0] = (uint32)f2b(h0) | ((uint32)f2b(h1) << 16);
        o[1] = (uint32)f2b(h2) | ((uint32)f2b(h3) << 16);
        ((uintx2*)out)[(size_t)i * 32 + c4] = o;
    }
}

extern "C" void kernel_launch(void* const* d_in, const int* in_sizes, int n_in,
                              void* d_out, int out_size, void* d_ws, size_t ws_size,
                              hipStream_t stream) {
    const float* x   = (const float*)d_in[0];
    const int* eidx  = (const int*)d_in[1];
    const float* W1  = (const float*)d_in[2];
    const float* b1  = (const float*)d_in[3];
    const float* W2  = (const float*)d_in[4];
    const float* b2  = (const float*)d_in[5];
    const float* lw1 = (const float*)d_in[6];
    const float* lb1 = (const float*)d_in[7];
    const float* lw2 = (const float*)d_in[8];
    const float* lb2 = (const float*)d_in[9];
    const float* lw3 = (const float*)d_in[10];
    const float* lb3 = (const float*)d_in[11];
    const float* lw4 = (const float*)d_in[12];
    const float* lb4 = (const float*)d_in[13];
    float* out = (float*)d_out;

    const int N = in_sizes[0] / 128;
    const int E = in_sizes[1] / 2;

    // workspace carve (256B aligned)
    char* p = (char*)d_ws;
    auto alloc = [&](size_t bytes) -> void* {
        void* q = (void*)p;
        p += (bytes + 255) & ~(size_t)255;
        return q;
    };
    float* dinv      = (float*)alloc((size_t)N * 4);
    int* rowp        = (int*)alloc((size_t)(N + 1) * 4);
    uint32* bkt_size = (uint32*)alloc(MAXBK * 4);
    uint32* bkt_base = (uint32*)alloc(MAXBK * 4);
    uint32* bkt_cur  = (uint32*)alloc(MAXBK * 4);
    int* csr         = (int*)alloc((size_t)E * 4);
    unsigned short* Wt_hi = (unsigned short*)alloc(5 * 16384 * 2);
    unsigned short* Wt_lo = (unsigned short*)alloc(5 * 16384 * 2);
    unsigned short* bufA  = (unsigned short*)alloc((size_t)(N + 1) * 128 * 2);
    unsigned short* bufB  = (unsigned short*)alloc((size_t)(N + 1) * 128 * 2);
    uint32* packed = (uint32*)bufA;  // alias: bytes [0, 4E) dead before gemm1 writes bufA

    const int MB4 = (N + 127) / 128;
    const int AB  = (N + 3) / 4;
    const int NCH = (E + CHUNK - 1) / CHUNK;
    const int NBK = (N + 255) >> 8;  // must be <= MAXBK

    // zero-row for agg padding (row N); packed alias covers < 4E = 12.8MB, row N at 25.6MB
    hipMemsetAsync(bufA + (size_t)N * 128, 0, 256, stream);
    hipMemsetAsync(bkt_size, 0, MAXBK * 4, stream);
    countb_k<<<NCH, 256, 0, stream>>>(eidx, bkt_size, E);
    prep_w6_k<<<320, 256, 0, stream>>>(W1, W2, lw1, lw2, lw3, Wt_hi, Wt_lo);
    scanb_k<<<1, MAXBK, 0, stream>>>(bkt_size, bkt_base, bkt_cur, NBK);
    scatterb_k<<<NCH, 256, 0, stream>>>(eidx, bkt_cur, packed, E);
    buildb_k<<<NBK, 256, 0, stream>>>(packed, bkt_base, bkt_size, rowp, dinv, csr, N, E);

    const unsigned short* WH = Wt_hi;
    const unsigned short* WL = Wt_lo;

    // conv1
    gemm_z_k<0><<<MB4, 256, 0, stream>>>(x, WH + 0 * 16384, WL + 0 * 16384, dinv, bufA, N);
    agg_tanh_k<<<AB, 256, 0, stream>>>((const uint32*)bufA, rowp, csr, dinv, b1,
                                       (uint32*)bufB, N);
    // conv2
    gemm_z_k<1><<<MB4, 256, 0, stream>>>(bufB, WH + 1 * 16384, WL + 1 * 16384, dinv, bufA, N);
    agg_tanh_k<<<AB, 256, 0, stream>>>((const uint32*)bufA, rowp, csr, dinv, b2,
                                       (uint32*)bufB, N);
    // fused MLP head (lw1..lw3 + lw4)
    mlp_fused_k<<<MB4, 256, 0, stream>>>(bufB, WH + 2 * 16384, WL + 2 * 16384,
                                         lb1, lb2, lb3, lw4, lb4, out, N);
}

// Round 7
// 589.937 us; speedup vs baseline: 2.0886x; 1.1428x over previous
//
#include <hip/hip_runtime.h>

typedef __attribute__((ext_vector_type(8))) short short8;
typedef __attribute__((ext_vector_type(4))) float floatx4;
typedef __attribute__((ext_vector_type(2))) unsigned int uintx2;
typedef unsigned int uint32;

__device__ inline float b2f(unsigned short u) {
    union { uint32 i; float f; } x; x.i = ((uint32)u) << 16; return x.f;
}
__device__ inline float bl(uint32 v) {
    union { uint32 i; float f; } x; x.i = v << 16; return x.f;
}
__device__ inline float bh(uint32 v) {
    union { uint32 i; float f; } x; x.i = v & 0xffff0000u; return x.f;
}
__device__ inline unsigned short f2b(float f) {
    union { float f; uint32 u; } x; x.f = f;
    uint32 r = x.u + 0x7fffu + ((x.u >> 16) & 1u);
    return (unsigned short)(r >> 16);
}
// tanh via v_exp_f32: t=2^(-2*log2e*|x|), tanh=sign(x)*(1-t)/(1+t).
// rel err ~1e-6, far below bf16 storage rounding (2^-8).
__device__ inline float fast_tanh(float x) {
    float ax = __builtin_fabsf(x);
    float t = __builtin_amdgcn_exp2f(-2.8853900817779268f * ax);
    float r = (1.0f - t) * __builtin_amdgcn_rcpf(1.0f + t);
    return __builtin_copysignf(r, x);
}

// ================= CSR build via 2-level bucket sort =================
// bucket b owns nodes [b*256, b*256+255]; csr layout is bucket-major ==
// dst-major, so bucket bases double as csr row-pointer bases.
// packed edge word: (src << 8) | (dst & 255)   (requires N < 2^24)

#define CHUNK 8192
#define MAXBK 512  // supports N <= 131072

__global__ __launch_bounds__(256) void countb_k(const int* __restrict__ eidx,
                                                uint32* __restrict__ bkt_size, int E) {
    __shared__ uint32 hist[MAXBK];
    int t = threadIdx.x;
    hist[t] = 0; hist[t + 256] = 0;
    __syncthreads();
    int base = blockIdx.x * CHUNK;
    int n = E - base; if (n > CHUNK) n = CHUNK;
    for (int i = t; i < n; i += 256) {
        int d = eidx[E + base + i];
        atomicAdd(&hist[d >> 8], 1u);
    }
    __syncthreads();
    uint32 c0 = hist[t], c1 = hist[t + 256];
    if (c0) atomicAdd(&bkt_size[t], c0);
    if (c1) atomicAdd(&bkt_size[t + 256], c1);
}

__global__ __launch_bounds__(MAXBK) void scanb_k(const uint32* __restrict__ bkt_size,
                                                 uint32* __restrict__ bkt_base,
                                                 uint32* __restrict__ bkt_cur, int nbk) {
    __shared__ uint32 s[MAXBK];
    int t = threadIdx.x;
    uint32 v = (t < nbk) ? bkt_size[t] : 0;
    s[t] = v;
    __syncthreads();
    for (int off = 1; off < MAXBK; off <<= 1) {
        uint32 x = (t >= off) ? s[t - off] : 0;
        __syncthreads();
        s[t] += x;
        __syncthreads();
    }
    uint32 excl = s[t] - v;
    bkt_base[t] = excl;
    bkt_cur[t] = excl;
}

__global__ __launch_bounds__(256) void scatterb_k(const int* __restrict__ eidx,
                                                  uint32* __restrict__ bkt_cur,
                                                  uint32* __restrict__ packed, int E) {
    __shared__ uint32 hist[MAXBK];
    __shared__ uint32 temp[256];
    __shared__ uint32 hsc[MAXBK + 1];
    __shared__ uint32 gbase[MAXBK];
    __shared__ uint32 lcur[MAXBK];
    __shared__ uint32 stage[CHUNK];
    int t = threadIdx.x;
    int cbase = blockIdx.x * CHUNK;
    int n = E - cbase; if (n > CHUNK) n = CHUNK;

    hist[t] = 0; hist[t + 256] = 0;
    __syncthreads();
    for (int i = t; i < n; i += 256) {
        int d = eidx[E + cbase + i];
        atomicAdd(&hist[d >> 8], 1u);
    }
    __syncthreads();
    uint32 c0 = hist[2 * t], c1 = hist[2 * t + 1];
    temp[t] = c0 + c1;
    __syncthreads();
    for (int off = 1; off < 256; off <<= 1) {
        uint32 x = (t >= off) ? temp[t - off] : 0;
        __syncthreads();
        temp[t] += x;
        __syncthreads();
    }
    uint32 exclp = temp[t] - (c0 + c1);
    hsc[2 * t] = exclp;
    hsc[2 * t + 1] = exclp + c0;
    if (t == 255) hsc[MAXBK] = temp[255];
    lcur[2 * t] = exclp;
    lcur[2 * t + 1] = exclp + c0;
    if (c0) gbase[2 * t] = atomicAdd(&bkt_cur[2 * t], c0);
    if (c1) gbase[2 * t + 1] = atomicAdd(&bkt_cur[2 * t + 1], c1);
    __syncthreads();
    for (int i = t; i < n; i += 256) {
        int s = eidx[cbase + i];
        int d = eidx[E + cbase + i];
        int b = d >> 8;
        uint32 pos = atomicAdd(&lcur[b], 1u);
        stage[pos] = ((uint32)s << 8) | (uint32)(d & 255);
    }
    __syncthreads();
    for (int i = t; i < n; i += 256) {
        int lo = 0, hi = MAXBK - 1;
        while (lo < hi) {
            int mid = (lo + hi + 1) >> 1;
            if (hsc[mid] <= (uint32)i) lo = mid; else hi = mid - 1;
        }
        packed[gbase[lo] + (i - hsc[lo])] = stage[i];
    }
}

__global__ __launch_bounds__(256) void buildb_k(const uint32* __restrict__ packed,
                                                const uint32* __restrict__ bkt_base,
                                                const uint32* __restrict__ bkt_size,
                                                int* __restrict__ rowp,
                                                float* __restrict__ dinv,
                                                int* __restrict__ csr, int N, int E) {
    __shared__ uint32 cnt[256];
    __shared__ uint32 incl[256];
    __shared__ uint32 cur[256];
    int t = threadIdx.x;
    int b = blockIdx.x;
    uint32 base = bkt_base[b];
    uint32 size = bkt_size[b];
    int node0 = b << 8;

    cnt[t] = 0;
    __syncthreads();
    for (uint32 i = t; i < size; i += 256)
        atomicAdd(&cnt[packed[base + i] & 255u], 1u);
    __syncthreads();
    uint32 v = cnt[t];
    incl[t] = v;
    __syncthreads();
    for (int off = 1; off < 256; off <<= 1) {
        uint32 x = (t >= off) ? incl[t - off] : 0;
        __syncthreads();
        incl[t] += x;
        __syncthreads();
    }
    uint32 loc = incl[t] - v;  // exclusive
    cur[t] = loc;
    int node = node0 + t;
    if (node < N) {
        dinv[node] = rsqrtf((float)v + 2.0f);
        rowp[node] = (int)(base + loc);
        if (node == N - 1) rowp[N] = E;
    }
    __syncthreads();
    for (uint32 i = t; i < size; i += 256) {
        uint32 p = packed[base + i];
        uint32 pos = atomicAdd(&cur[p & 255u], 1u);
        csr[base + pos] = (int)(p >> 8);
    }
}

// ------- weight prep: W fp32 [128][128] -> Wt_hi/Wt_lo bf16 (transposed)

__global__ __launch_bounds__(256) void prep_w6_k(const float* __restrict__ w0,
                                                 const float* __restrict__ w1,
                                                 const float* __restrict__ w2,
                                                 const float* __restrict__ w3,
                                                 const float* __restrict__ w4,
                                                 unsigned short* __restrict__ Wt_hi,
                                                 unsigned short* __restrict__ Wt_lo) {
    int widx = blockIdx.x >> 6;  // 64 blocks per weight
    const float* W;
    switch (widx) {
        case 0: W = w0; break;
        case 1: W = w1; break;
        case 2: W = w2; break;
        case 3: W = w3; break;
        default: W = w4; break;
    }
    int t = (blockIdx.x & 63) * 256 + threadIdx.x;
    int c = t & 127, k = t >> 7;
    float w = W[k * 128 + c];
    unsigned short hi = f2b(w);
    float lo = w - b2f(hi);
    Wt_hi[widx * 16384 + c * 128 + k] = hi;
    Wt_lo[widx * 16384 + c * 128 + k] = f2b(lo);
}

// ---------------- conv GEMM: z = dinv * (A @ W), 128 rows/block, 32 rows/wave --------
// ASRC 0: A fp32;  ASRC 1: A bf16 storage.

template <int ASRC>
__global__ __launch_bounds__(256) void gemm_z_k(
    const void* __restrict__ Asrc,
    const unsigned short* __restrict__ Wt_hi,
    const unsigned short* __restrict__ Wt_lo,
    const float* __restrict__ dinv,
    unsigned short* __restrict__ out, int N) {
    int tid = threadIdx.x;
    int wave = tid >> 6, lane = tid & 63;
    int quad = lane >> 4, r = lane & 15;
    int m32 = blockIdx.x * 128 + wave * 32;

    short8 af[2][4];
#pragma unroll
    for (int s = 0; s < 2; ++s) {
        int rowA = m32 + s * 16 + r;
        if (rowA >= N) rowA = N - 1;
        if (ASRC == 0) {
            const float4* Af = (const float4*)Asrc;
#pragma unroll
            for (int kc = 0; kc < 4; ++kc) {
                float4 p0 = Af[((size_t)rowA * 128 + kc * 32 + quad * 8) >> 2];
                float4 p1 = Af[(((size_t)rowA * 128 + kc * 32 + quad * 8) >> 2) + 1];
                short8 a;
                a[0] = (short)f2b(p0.x); a[1] = (short)f2b(p0.y);
                a[2] = (short)f2b(p0.z); a[3] = (short)f2b(p0.w);
                a[4] = (short)f2b(p1.x); a[5] = (short)f2b(p1.y);
                a[6] = (short)f2b(p1.z); a[7] = (short)f2b(p1.w);
                af[s][kc] = a;
            }
        } else {
            const short* Ap = (const short*)Asrc;
#pragma unroll
            for (int kc = 0; kc < 4; ++kc)
                af[s][kc] = *(const short8*)(Ap + (size_t)rowA * 128 + kc * 32 + quad * 8);
        }
    }

    float dv[2][4];
#pragma unroll
    for (int s = 0; s < 2; ++s)
#pragma unroll
        for (int reg = 0; reg < 4; ++reg) {
            int i = m32 + s * 16 + quad * 4 + reg;
            dv[s][reg] = dinv[i < N ? i : N - 1];
        }

    const short* Wh = (const short*)Wt_hi;
    const short* Wl = (const short*)Wt_lo;

#pragma unroll
    for (int ct = 0; ct < 8; ++ct) {
        int n = ct * 16 + r;
        floatx4 a0 = {0.f, 0.f, 0.f, 0.f}, a1 = {0.f, 0.f, 0.f, 0.f};
#pragma unroll
        for (int kc = 0; kc < 4; ++kc) {
            short8 bh8 = *(const short8*)(Wh + n * 128 + kc * 32 + quad * 8);
            a0 = __builtin_amdgcn_mfma_f32_16x16x32_bf16(af[0][kc], bh8, a0, 0, 0, 0);
            a1 = __builtin_amdgcn_mfma_f32_16x16x32_bf16(af[1][kc], bh8, a1, 0, 0, 0);
            short8 bl8 = *(const short8*)(Wl + n * 128 + kc * 32 + quad * 8);
            a0 = __builtin_amdgcn_mfma_f32_16x16x32_bf16(af[0][kc], bl8, a0, 0, 0, 0);
            a1 = __builtin_amdgcn_mfma_f32_16x16x32_bf16(af[1][kc], bl8, a1, 0, 0, 0);
        }
#pragma unroll
        for (int reg = 0; reg < 4; ++reg) {
            int i0 = m32 + quad * 4 + reg;
            if (i0 < N) out[(size_t)i0 * 128 + n] = f2b(a0[reg] * dv[0][reg]);
            int i1 = m32 + 16 + quad * 4 + reg;
            if (i1 < N) out[(size_t)i1 * 128 + n] = f2b(a1[reg] * dv[1][reg]);
        }
    }
}

// ---------------- fused MLP head: h2 -> tanh^3 chain -> [N,3] fp32 ----------------
// 128 rows/block, 32 rows/wave. Per-wave LDS tile round-trips C-layout -> A-layout
// between layers (no barriers: each wave consumes only its own tile).
// launch_bounds(256,2): LDS caps at 4 blocks/CU anyway -> spend VGPRs on ILP.

#define LSTR 136  // LDS row stride in shorts (128 + 8 pad)

__global__ __launch_bounds__(256, 2) void mlp_fused_k(
    const unsigned short* __restrict__ H,
    const unsigned short* __restrict__ WH,   // lw1,lw2,lw3 hi at L*16384
    const unsigned short* __restrict__ WL,
    const float* __restrict__ lb1, const float* __restrict__ lb2,
    const float* __restrict__ lb3,
    const float* __restrict__ W4, const float* __restrict__ b4,
    float* __restrict__ out, int N) {
    __shared__ unsigned short tile[4][32 * LSTR];
    __shared__ float w4s[384];
    int tid = threadIdx.x;
    if (tid < 192) { w4s[tid] = W4[tid]; w4s[tid + 192] = W4[tid + 192]; }
    __syncthreads();

    int wave = tid >> 6, lane = tid & 63;
    int quad = lane >> 4, r = lane & 15;
    unsigned short* T = tile[wave];
    int m32 = blockIdx.x * 128 + wave * 32;

    short8 af[2][4];
    const short* Hp = (const short*)H;
#pragma unroll
    for (int s = 0; s < 2; ++s) {
        int rowA = m32 + s * 16 + r;
        if (rowA >= N) rowA = N - 1;
#pragma unroll
        for (int kc = 0; kc < 4; ++kc)
            af[s][kc] = *(const short8*)(Hp + (size_t)rowA * 128 + kc * 32 + quad * 8);
    }

    const float* biases[3] = {lb1, lb2, lb3};
#pragma unroll
    for (int L = 0; L < 3; ++L) {
        const short* Wh = (const short*)WH + L * 16384;
        const short* Wl = (const short*)WL + L * 16384;
        const float* bias = biases[L];
#pragma unroll
        for (int ct = 0; ct < 8; ++ct) {
            int n = ct * 16 + r;
            floatx4 a0 = {0.f, 0.f, 0.f, 0.f}, a1 = {0.f, 0.f, 0.f, 0.f};
#pragma unroll
            for (int kc = 0; kc < 4; ++kc) {
                short8 bh8 = *(const short8*)(Wh + n * 128 + kc * 32 + quad * 8);
                a0 = __builtin_amdgcn_mfma_f32_16x16x32_bf16(af[0][kc], bh8, a0, 0, 0, 0);
                a1 = __builtin_amdgcn_mfma_f32_16x16x32_bf16(af[1][kc], bh8, a1, 0, 0, 0);
                short8 bl8 = *(const short8*)(Wl + n * 128 + kc * 32 + quad * 8);
                a0 = __builtin_amdgcn_mfma_f32_16x16x32_bf16(af[0][kc], bl8, a0, 0, 0, 0);
                a1 = __builtin_amdgcn_mfma_f32_16x16x32_bf16(af[1][kc], bl8, a1, 0, 0, 0);
            }
            float bv = bias[n];
#pragma unroll
            for (int reg = 0; reg < 4; ++reg) {
                int lrow = quad * 4 + reg;
                T[lrow * LSTR + n] = f2b(fast_tanh(a0[reg] + bv));
                T[(lrow + 16) * LSTR + n] = f2b(fast_tanh(a1[reg] + bv));
            }
        }
        // C-layout tile -> A-fragments for next layer (same wave; lgkmcnt only)
        if (L < 2) {
#pragma unroll
            for (int s = 0; s < 2; ++s)
#pragma unroll
                for (int kc = 0; kc < 4; ++kc)
                    af[s][kc] = *(const short8*)&T[(s * 16 + r) * LSTR + kc * 32 + quad * 8];
        }
    }

    // layer 4: lane handles row (lane&31), channel half (lane>>5)
    int lrow = lane & 31;
    int halfc = lane >> 5;
    float a0 = 0.f, a1 = 0.f, a2 = 0.f;
#pragma unroll
    for (int c8 = 0; c8 < 8; ++c8) {
        int cbase = halfc * 64 + c8 * 8;
        short8 hv = *(const short8*)&T[lrow * LSTR + cbase];
#pragma unroll
        for (int j = 0; j < 8; ++j) {
            float xv = b2f((unsigned short)hv[j]);
            int ch = cbase + j;
            a0 = fmaf(xv, w4s[ch * 3 + 0], a0);
            a1 = fmaf(xv, w4s[ch * 3 + 1], a1);
            a2 = fmaf(xv, w4s[ch * 3 + 2], a2);
        }
    }
    a0 += __shfl_xor(a0, 32);
    a1 += __shfl_xor(a1, 32);
    a2 += __shfl_xor(a2, 32);
    if (halfc == 0) {
        int i = m32 + lrow;
        if (i < N) {
            out[(size_t)i * 3 + 0] = a0 + b4[0];
            out[(size_t)i * 3 + 1] = a1 + b4[1];
            out[(size_t)i * 3 + 2] = a2 + b4[2];
        }
    }
}

// ---------------- Aggregation: h[i] = tanh(dinv_i*(sum_e z[src_e] + 2 z_i) + b) --------
// One wave per node; lanes 0-31 even edges, 32-63 odd; 4 channels (8B) per lane.
// Pad lanes use src = N -> zeroed z row (no per-edge masking VALU).

__global__ __launch_bounds__(256) void agg_tanh_k(
    const uint32* __restrict__ z, const int* __restrict__ rowp,
    const int* __restrict__ csr, const float* __restrict__ dinv,
    const float* __restrict__ bias, uint32* __restrict__ out, int N) {
    int lane = threadIdx.x & 63;
    int half = lane >> 5;
    int c4 = lane & 31;
    int i = blockIdx.x * 4 + (threadIdx.x >> 6);
    if (i >= N) return;
    int start = rowp[i], end = rowp[i + 1];
    const uintx2* z2 = (const uintx2*)z;
    float a0 = 0.f, a1 = 0.f, a2 = 0.f, a3 = 0.f;
    for (int e = start; e < end; e += 64) {
        int cnt = end - e;
        if (cnt > 64) cnt = 64;
        int s = (lane < cnt) ? csr[e + lane] : N;  // N = zero row
        int mp = (cnt + 15) & ~15;
        for (int m = 0; m < mp; m += 16) {
            uintx2 v[8];
#pragma unroll
            for (int p = 0; p < 8; ++p) {
                int sj = __shfl(s, m + 2 * p + half);
                v[p] = z2[(size_t)sj * 32 + c4];
            }
#pragma unroll
            for (int p = 0; p < 8; ++p) {
                a0 += bl(v[p][0]);
                a1 += bh(v[p][0]);
                a2 += bl(v[p][1]);
                a3 += bh(v[p][1]);
            }
        }
    }
    a0 += __shfl_xor(a0, 32);
    a1 += __shfl_xor(a1, 32);
    a2 += __shfl_xor(a2, 32);
    a3 += __shfl_xor(a3, 32);
    if (half == 0) {
        uintx2 vi = z2[(size_t)i * 32 + c4];
        a0 += 2.f * bl(vi[0]);
        a1 += 2.f * bh(vi[0]);
        a2 += 2.f * bl(vi[1]);
        a3 += 2.f * bh(vi[1]);
        float di = dinv[i];
        float4 bv = ((const float4*)bias)[c4];
        float h0 = fast_tanh(fmaf(di, a0, bv.x));
        float h1 = fast_tanh(fmaf(di, a1, bv.y));
        float h2 = fast_tanh(fmaf(di, a2, bv.z));
        float h3 = fast_tanh(fmaf(di, a3, bv.w));
        uintx2 o;
        o[0] = (uint32)f2b(h0) | ((uint32)f2b(h1) << 16);
        o[1] = (uint32)f2b(h2) | ((uint32)f2b(h3) << 16);
        ((uintx2*)out)[(size_t)i * 32 + c4] = o;
    }
}

extern "C" void kernel_launch(void* const* d_in, const int* in_sizes, int n_in,
                              void* d_out, int out_size, void* d_ws, size_t ws_size,
                              hipStream_t stream) {
    const float* x   = (const float*)d_in[0];
    const int* eidx  = (const int*)d_in[1];
    const float* W1  = (const float*)d_in[2];
    const float* b1  = (const float*)d_in[3];
    const float* W2  = (const float*)d_in[4];
    const float* b2  = (const float*)d_in[5];
    const float* lw1 = (const float*)d_in[6];
    const float* lb1 = (const float*)d_in[7];
    const float* lw2 = (const float*)d_in[8];
    const float* lb2 = (const float*)d_in[9];
    const float* lw3 = (const float*)d_in[10];
    const float* lb3 = (const float*)d_in[11];
    const float* lw4 = (const float*)d_in[12];
    const float* lb4 = (const float*)d_in[13];
    float* out = (float*)d_out;

    const int N = in_sizes[0] / 128;
    const int E = in_sizes[1] / 2;

    // workspace carve (256B aligned)
    char* p = (char*)d_ws;
    auto alloc = [&](size_t bytes) -> void* {
        void* q = (void*)p;
        p += (bytes + 255) & ~(size_t)255;
        return q;
    };
    float* dinv      = (float*)alloc((size_t)N * 4);
    int* rowp        = (int*)alloc((size_t)(N + 1) * 4);
    uint32* bkt_size = (uint32*)alloc(MAXBK * 4);
    uint32* bkt_base = (uint32*)alloc(MAXBK * 4);
    uint32* bkt_cur  = (uint32*)alloc(MAXBK * 4);
    int* csr         = (int*)alloc((size_t)E * 4);
    unsigned short* Wt_hi = (unsigned short*)alloc(5 * 16384 * 2);
    unsigned short* Wt_lo = (unsigned short*)alloc(5 * 16384 * 2);
    unsigned short* bufA  = (unsigned short*)alloc((size_t)(N + 1) * 128 * 2);
    unsigned short* bufB  = (unsigned short*)alloc((size_t)(N + 1) * 128 * 2);
    uint32* packed = (uint32*)bufA;  // alias: bytes [0, 4E) dead before gemm1 writes bufA

    const int MB4 = (N + 127) / 128;
    const int AB  = (N + 3) / 4;
    const int NCH = (E + CHUNK - 1) / CHUNK;
    const int NBK = (N + 255) >> 8;  // must be <= MAXBK

    // zero-row for agg padding (row N); packed alias covers < 4E = 12.8MB, row N at 25.6MB
    hipMemsetAsync(bufA + (size_t)N * 128, 0, 256, stream);
    hipMemsetAsync(bkt_size, 0, MAXBK * 4, stream);
    countb_k<<<NCH, 256, 0, stream>>>(eidx, bkt_size, E);
    prep_w6_k<<<320, 256, 0, stream>>>(W1, W2, lw1, lw2, lw3, Wt_hi, Wt_lo);
    scanb_k<<<1, MAXBK, 0, stream>>>(bkt_size, bkt_base, bkt_cur, NBK);
    scatterb_k<<<NCH, 256, 0, stream>>>(eidx, bkt_cur, packed, E);
    buildb_k<<<NBK, 256, 0, stream>>>(packed, bkt_base, bkt_size, rowp, dinv, csr, N, E);

    const unsigned short* WH = Wt_hi;
    const unsigned short* WL = Wt_lo;

    // conv1
    gemm_z_k<0><<<MB4, 256, 0, stream>>>(x, WH + 0 * 16384, WL + 0 * 16384, dinv, bufA, N);
    agg_tanh_k<<<AB, 256, 0, stream>>>((const uint32*)bufA, rowp, csr, dinv, b1,
                                       (uint32*)bufB, N);
    // conv2
    gemm_z_k<1><<<MB4, 256, 0, stream>>>(bufB, WH + 1 * 16384, WL + 1 * 16384, dinv, bufA, N);
    agg_tanh_k<<<AB, 256, 0, stream>>>((const uint32*)bufA, rowp, csr, dinv, b2,
                                       (uint32*)bufB, N);
    // fused MLP head (lw1..lw3 + lw4)
    mlp_fused_k<<<MB4, 256, 0, stream>>>(bufB, WH + 2 * 16384, WL + 2 * 16384,
                                         lb1, lb2, lb3, lw4, lb4, out, N);
}

// Round 8
// 570.435 us; speedup vs baseline: 2.1600x; 1.0342x over previous
//
#include <hip/hip_runtime.h>

typedef __attribute__((ext_vector_type(8))) short short8;
typedef __attribute__((ext_vector_type(4))) float floatx4;
typedef unsigned int uint32;

__device__ inline float b2f(unsigned short u) {
    union { uint32 i; float f; } x; x.i = ((uint32)u) << 16; return x.f;
}
__device__ inline float bl(uint32 v) {
    union { uint32 i; float f; } x; x.i = v << 16; return x.f;
}
__device__ inline float bh(uint32 v) {
    union { uint32 i; float f; } x; x.i = v & 0xffff0000u; return x.f;
}
__device__ inline unsigned short f2b(float f) {
    union { float f; uint32 u; } x; x.f = f;
    uint32 r = x.u + 0x7fffu + ((x.u >> 16) & 1u);
    return (unsigned short)(r >> 16);
}
// tanh via v_exp_f32: t=2^(-2*log2e*|x|), tanh=sign(x)*(1-t)/(1+t).
// rel err ~1e-6, far below bf16 storage rounding (2^-8).
__device__ inline float fast_tanh(float x) {
    float ax = __builtin_fabsf(x);
    float t = __builtin_amdgcn_exp2f(-2.8853900817779268f * ax);
    float r = (1.0f - t) * __builtin_amdgcn_rcpf(1.0f + t);
    return __builtin_copysignf(r, x);
}

// ================= CSR build via 2-level bucket sort =================
// bucket b owns nodes [b*256, b*256+255]; csr layout is bucket-major ==
// dst-major, so bucket bases double as csr row-pointer bases.
// packed edge word: (src << 8) | (dst & 255)   (requires N < 2^24)

#define CHUNK 8192
#define MAXBK 512  // supports N <= 131072

__global__ __launch_bounds__(256) void countb_k(const int* __restrict__ eidx,
                                                uint32* __restrict__ bkt_size, int E) {
    __shared__ uint32 hist[MAXBK];
    int t = threadIdx.x;
    hist[t] = 0; hist[t + 256] = 0;
    __syncthreads();
    int base = blockIdx.x * CHUNK;
    int n = E - base; if (n > CHUNK) n = CHUNK;
    for (int i = t; i < n; i += 256) {
        int d = eidx[E + base + i];
        atomicAdd(&hist[d >> 8], 1u);
    }
    __syncthreads();
    uint32 c0 = hist[t], c1 = hist[t + 256];
    if (c0) atomicAdd(&bkt_size[t], c0);
    if (c1) atomicAdd(&bkt_size[t + 256], c1);
}

__global__ __launch_bounds__(MAXBK) void scanb_k(const uint32* __restrict__ bkt_size,
                                                 uint32* __restrict__ bkt_base,
                                                 uint32* __restrict__ bkt_cur, int nbk) {
    __shared__ uint32 s[MAXBK];
    int t = threadIdx.x;
    uint32 v = (t < nbk) ? bkt_size[t] : 0;
    s[t] = v;
    __syncthreads();
    for (int off = 1; off < MAXBK; off <<= 1) {
        uint32 x = (t >= off) ? s[t - off] : 0;
        __syncthreads();
        s[t] += x;
        __syncthreads();
    }
    uint32 excl = s[t] - v;
    bkt_base[t] = excl;
    bkt_cur[t] = excl;
}

__global__ __launch_bounds__(256) void scatterb_k(const int* __restrict__ eidx,
                                                  uint32* __restrict__ bkt_cur,
                                                  uint32* __restrict__ packed, int E) {
    __shared__ uint32 hist[MAXBK];
    __shared__ uint32 temp[256];
    __shared__ uint32 hsc[MAXBK];
    __shared__ uint32 gbase[MAXBK];
    __shared__ uint32 lcur[MAXBK];
    __shared__ uint32 stage[CHUNK];
    __shared__ unsigned short stgb[CHUNK];  // bucket id per staged slot
    int t = threadIdx.x;
    int cbase = blockIdx.x * CHUNK;
    int n = E - cbase; if (n > CHUNK) n = CHUNK;

    hist[t] = 0; hist[t + 256] = 0;
    __syncthreads();
    for (int i = t; i < n; i += 256) {
        int d = eidx[E + cbase + i];
        atomicAdd(&hist[d >> 8], 1u);
    }
    __syncthreads();
    uint32 c0 = hist[2 * t], c1 = hist[2 * t + 1];
    temp[t] = c0 + c1;
    __syncthreads();
    for (int off = 1; off < 256; off <<= 1) {
        uint32 x = (t >= off) ? temp[t - off] : 0;
        __syncthreads();
        temp[t] += x;
        __syncthreads();
    }
    uint32 exclp = temp[t] - (c0 + c1);
    hsc[2 * t] = exclp;
    hsc[2 * t + 1] = exclp + c0;
    lcur[2 * t] = exclp;
    lcur[2 * t + 1] = exclp + c0;
    if (c0) gbase[2 * t] = atomicAdd(&bkt_cur[2 * t], c0);
    if (c1) gbase[2 * t + 1] = atomicAdd(&bkt_cur[2 * t + 1], c1);
    __syncthreads();
    for (int i = t; i < n; i += 256) {
        int s = eidx[cbase + i];
        int d = eidx[E + cbase + i];
        int b = d >> 8;
        uint32 pos = atomicAdd(&lcur[b], 1u);
        stage[pos] = ((uint32)s << 8) | (uint32)(d & 255);
        stgb[pos] = (unsigned short)b;
    }
    __syncthreads();
    // write out: consecutive threads -> consecutive addresses within segment
    for (int i = t; i < n; i += 256) {
        int b = stgb[i];
        packed[gbase[b] + (i - hsc[b])] = stage[i];
    }
}

__global__ __launch_bounds__(256) void buildb_k(const uint32* __restrict__ packed,
                                                const uint32* __restrict__ bkt_base,
                                                const uint32* __restrict__ bkt_size,
                                                int* __restrict__ rowp,
                                                float* __restrict__ dinv,
                                                int* __restrict__ csr, int N, int E) {
    __shared__ uint32 cnt[256];
    __shared__ uint32 incl[256];
    __shared__ uint32 cur[256];
    int t = threadIdx.x;
    int b = blockIdx.x;
    uint32 base = bkt_base[b];
    uint32 size = bkt_size[b];
    int node0 = b << 8;

    cnt[t] = 0;
    __syncthreads();
    for (uint32 i = t; i < size; i += 256)
        atomicAdd(&cnt[packed[base + i] & 255u], 1u);
    __syncthreads();
    uint32 v = cnt[t];
    incl[t] = v;
    __syncthreads();
    for (int off = 1; off < 256; off <<= 1) {
        uint32 x = (t >= off) ? incl[t - off] : 0;
        __syncthreads();
        incl[t] += x;
        __syncthreads();
    }
    uint32 loc = incl[t] - v;  // exclusive
    cur[t] = loc;
    int node = node0 + t;
    if (node < N) {
        dinv[node] = rsqrtf((float)v + 2.0f);
        rowp[node] = (int)(base + loc);
        if (node == N - 1) rowp[N] = E;
    }
    __syncthreads();
    for (uint32 i = t; i < size; i += 256) {
        uint32 p = packed[base + i];
        uint32 pos = atomicAdd(&cur[p & 255u], 1u);
        csr[base + pos] = (int)(p >> 8);
    }
}

// ------- weight prep: W fp32 [128][128] -> Wt_hi/Wt_lo bf16 (transposed)

__global__ __launch_bounds__(256) void prep_w6_k(const float* __restrict__ w0,
                                                 const float* __restrict__ w1,
                                                 const float* __restrict__ w2,
                                                 const float* __restrict__ w3,
                                                 const float* __restrict__ w4,
                                                 unsigned short* __restrict__ Wt_hi,
                                                 unsigned short* __restrict__ Wt_lo) {
    int widx = blockIdx.x >> 6;  // 64 blocks per weight
    const float* W;
    switch (widx) {
        case 0: W = w0; break;
        case 1: W = w1; break;
        case 2: W = w2; break;
        case 3: W = w3; break;
        default: W = w4; break;
    }
    int t = (blockIdx.x & 63) * 256 + threadIdx.x;
    int c = t & 127, k = t >> 7;
    float w = W[k * 128 + c];
    unsigned short hi = f2b(w);
    float lo = w - b2f(hi);
    Wt_hi[widx * 16384 + c * 128 + k] = hi;
    Wt_lo[widx * 16384 + c * 128 + k] = f2b(lo);
}

// ---------------- conv GEMM: z = dinv * (A @ W), 128 rows/block, 32 rows/wave --------
// ASRC 0: A fp32;  ASRC 1: A bf16 storage.

template <int ASRC>
__global__ __launch_bounds__(256) void gemm_z_k(
    const void* __restrict__ Asrc,
    const unsigned short* __restrict__ Wt_hi,
    const unsigned short* __restrict__ Wt_lo,
    const float* __restrict__ dinv,
    unsigned short* __restrict__ out, int N) {
    int tid = threadIdx.x;
    int wave = tid >> 6, lane = tid & 63;
    int quad = lane >> 4, r = lane & 15;
    int m32 = blockIdx.x * 128 + wave * 32;

    short8 af[2][4];
#pragma unroll
    for (int s = 0; s < 2; ++s) {
        int rowA = m32 + s * 16 + r;
        if (rowA >= N) rowA = N - 1;
        if (ASRC == 0) {
            const float4* Af = (const float4*)Asrc;
#pragma unroll
            for (int kc = 0; kc < 4; ++kc) {
                float4 p0 = Af[((size_t)rowA * 128 + kc * 32 + quad * 8) >> 2];
                float4 p1 = Af[(((size_t)rowA * 128 + kc * 32 + quad * 8) >> 2) + 1];
                short8 a;
                a[0] = (short)f2b(p0.x); a[1] = (short)f2b(p0.y);
                a[2] = (short)f2b(p0.z); a[3] = (short)f2b(p0.w);
                a[4] = (short)f2b(p1.x); a[5] = (short)f2b(p1.y);
                a[6] = (short)f2b(p1.z); a[7] = (short)f2b(p1.w);
                af[s][kc] = a;
            }
        } else {
            const short* Ap = (const short*)Asrc;
#pragma unroll
            for (int kc = 0; kc < 4; ++kc)
                af[s][kc] = *(const short8*)(Ap + (size_t)rowA * 128 + kc * 32 + quad * 8);
        }
    }

    float dv[2][4];
#pragma unroll
    for (int s = 0; s < 2; ++s)
#pragma unroll
        for (int reg = 0; reg < 4; ++reg) {
            int i = m32 + s * 16 + quad * 4 + reg;
            dv[s][reg] = dinv[i < N ? i : N - 1];
        }

    const short* Wh = (const short*)Wt_hi;
    const short* Wl = (const short*)Wt_lo;

#pragma unroll
    for (int ct = 0; ct < 8; ++ct) {
        int n = ct * 16 + r;
        floatx4 a0 = {0.f, 0.f, 0.f, 0.f}, a1 = {0.f, 0.f, 0.f, 0.f};
#pragma unroll
        for (int kc = 0; kc < 4; ++kc) {
            short8 bh8 = *(const short8*)(Wh + n * 128 + kc * 32 + quad * 8);
            a0 = __builtin_amdgcn_mfma_f32_16x16x32_bf16(af[0][kc], bh8, a0, 0, 0, 0);
            a1 = __builtin_amdgcn_mfma_f32_16x16x32_bf16(af[1][kc], bh8, a1, 0, 0, 0);
            short8 bl8 = *(const short8*)(Wl + n * 128 + kc * 32 + quad * 8);
            a0 = __builtin_amdgcn_mfma_f32_16x16x32_bf16(af[0][kc], bl8, a0, 0, 0, 0);
            a1 = __builtin_amdgcn_mfma_f32_16x16x32_bf16(af[1][kc], bl8, a1, 0, 0, 0);
        }
#pragma unroll
        for (int reg = 0; reg < 4; ++reg) {
            int i0 = m32 + quad * 4 + reg;
            if (i0 < N) out[(size_t)i0 * 128 + n] = f2b(a0[reg] * dv[0][reg]);
            int i1 = m32 + 16 + quad * 4 + reg;
            if (i1 < N) out[(size_t)i1 * 128 + n] = f2b(a1[reg] * dv[1][reg]);
        }
    }
}

// ---------------- fused MLP head: h2 -> tanh^3 chain -> [N,3] fp32 ----------------
// 128 rows/block, 32 rows/wave. Per-wave LDS tile round-trips C-layout -> A-layout
// between layers (no barriers: each wave consumes only its own tile).
// launch_bounds(256,2): LDS caps at 4 blocks/CU anyway -> spend VGPRs on ILP.

#define LSTR 136  // LDS row stride in shorts (128 + 8 pad)

__global__ __launch_bounds__(256, 2) void mlp_fused_k(
    const unsigned short* __restrict__ H,
    const unsigned short* __restrict__ WH,   // lw1,lw2,lw3 hi at L*16384
    const unsigned short* __restrict__ WL,
    const float* __restrict__ lb1, const float* __restrict__ lb2,
    const float* __restrict__ lb3,
    const float* __restrict__ W4, const float* __restrict__ b4,
    float* __restrict__ out, int N) {
    __shared__ unsigned short tile[4][32 * LSTR];
    __shared__ float w4s[384];
    int tid = threadIdx.x;
    if (tid < 192) { w4s[tid] = W4[tid]; w4s[tid + 192] = W4[tid + 192]; }
    __syncthreads();

    int wave = tid >> 6, lane = tid & 63;
    int quad = lane >> 4, r = lane & 15;
    unsigned short* T = tile[wave];
    int m32 = blockIdx.x * 128 + wave * 32;

    short8 af[2][4];
    const short* Hp = (const short*)H;
#pragma unroll
    for (int s = 0; s < 2; ++s) {
        int rowA = m32 + s * 16 + r;
        if (rowA >= N) rowA = N - 1;
#pragma unroll
        for (int kc = 0; kc < 4; ++kc)
            af[s][kc] = *(const short8*)(Hp + (size_t)rowA * 128 + kc * 32 + quad * 8);
    }

    const float* biases[3] = {lb1, lb2, lb3};
#pragma unroll
    for (int L = 0; L < 3; ++L) {
        const short* Wh = (const short*)WH + L * 16384;
        const short* Wl = (const short*)WL + L * 16384;
        const float* bias = biases[L];
#pragma unroll
        for (int ct = 0; ct < 8; ++ct) {
            int n = ct * 16 + r;
            floatx4 a0 = {0.f, 0.f, 0.f, 0.f}, a1 = {0.f, 0.f, 0.f, 0.f};
#pragma unroll
            for (int kc = 0; kc < 4; ++kc) {
                short8 bh8 = *(const short8*)(Wh + n * 128 + kc * 32 + quad * 8);
                a0 = __builtin_amdgcn_mfma_f32_16x16x32_bf16(af[0][kc], bh8, a0, 0, 0, 0);
                a1 = __builtin_amdgcn_mfma_f32_16x16x32_bf16(af[1][kc], bh8, a1, 0, 0, 0);
                short8 bl8 = *(const short8*)(Wl + n * 128 + kc * 32 + quad * 8);
                a0 = __builtin_amdgcn_mfma_f32_16x16x32_bf16(af[0][kc], bl8, a0, 0, 0, 0);
                a1 = __builtin_amdgcn_mfma_f32_16x16x32_bf16(af[1][kc], bl8, a1, 0, 0, 0);
            }
            float bv = bias[n];
#pragma unroll
            for (int reg = 0; reg < 4; ++reg) {
                int lrow = quad * 4 + reg;
                T[lrow * LSTR + n] = f2b(fast_tanh(a0[reg] + bv));
                T[(lrow + 16) * LSTR + n] = f2b(fast_tanh(a1[reg] + bv));
            }
        }
        // C-layout tile -> A-fragments for next layer (same wave; lgkmcnt only)
        if (L < 2) {
#pragma unroll
            for (int s = 0; s < 2; ++s)
#pragma unroll
                for (int kc = 0; kc < 4; ++kc)
                    af[s][kc] = *(const short8*)&T[(s * 16 + r) * LSTR + kc * 32 + quad * 8];
        }
    }

    // layer 4: lane handles row (lane&31), channel half (lane>>5)
    int lrow = lane & 31;
    int halfc = lane >> 5;
    float a0 = 0.f, a1 = 0.f, a2 = 0.f;
#pragma unroll
    for (int c8 = 0; c8 < 8; ++c8) {
        int cbase = halfc * 64 + c8 * 8;
        short8 hv = *(const short8*)&T[lrow * LSTR + cbase];
#pragma unroll
        for (int j = 0; j < 8; ++j) {
            float xv = b2f((unsigned short)hv[j]);
            int ch = cbase + j;
            a0 = fmaf(xv, w4s[ch * 3 + 0], a0);
            a1 = fmaf(xv, w4s[ch * 3 + 1], a1);
            a2 = fmaf(xv, w4s[ch * 3 + 2], a2);
        }
    }
    a0 += __shfl_xor(a0, 32);
    a1 += __shfl_xor(a1, 32);
    a2 += __shfl_xor(a2, 32);
    if (halfc == 0) {
        int i = m32 + lrow;
        if (i < N) {
            out[(size_t)i * 3 + 0] = a0 + b4[0];
            out[(size_t)i * 3 + 1] = a1 + b4[1];
            out[(size_t)i * 3 + 2] = a2 + b4[2];
        }
    }
}

// -------- Aggregation, channel-split: one pass covers 64 of 128 channels --------
// h[i][ch] = tanh(dinv_i*(sum_e z[src_e][ch] + 2 z_i[ch]) + b[ch]) for ch in pass.
// One wave per node; lanes 0-31 even edges, 32-63 odd; each lane 2 channels (uint).
// Working set per pass = 12.8 MB (half rows, 64B-line aligned) -> higher L2 hit.
// Pad lanes use src = N -> zeroed z row (no per-edge masking VALU).

__global__ __launch_bounds__(256) void agg_half_k(
    const uint32* __restrict__ z, const int* __restrict__ rowp,
    const int* __restrict__ csr, const float* __restrict__ dinv,
    const float* __restrict__ bias, uint32* __restrict__ out, int N, int zoff) {
    int lane = threadIdx.x & 63;
    int half = lane >> 5;
    int c4 = lane & 31;
    int i = blockIdx.x * 4 + (threadIdx.x >> 6);
    if (i >= N) return;
    int start = rowp[i], end = rowp[i + 1];
    const uint32* zh = z + zoff + c4;  // lane-fixed column within row
    float a0 = 0.f, a1 = 0.f;
    for (int e = start; e < end; e += 64) {
        int cnt = end - e;
        if (cnt > 64) cnt = 64;
        int s = (lane < cnt) ? csr[e + lane] : N;  // N = zero row
        int mp = (cnt + 15) & ~15;
        for (int m = 0; m < mp; m += 16) {
            uint32 v[8];
#pragma unroll
            for (int p = 0; p < 8; ++p) {
                int sj = __shfl(s, m + 2 * p + half);
                v[p] = zh[(size_t)sj << 6];
            }
#pragma unroll
            for (int p = 0; p < 8; ++p) {
                a0 += bl(v[p]);
                a1 += bh(v[p]);
            }
        }
    }
    a0 += __shfl_xor(a0, 32);
    a1 += __shfl_xor(a1, 32);
    if (half == 0) {
        uint32 vi = zh[(size_t)i << 6];
        a0 += 2.f * bl(vi);
        a1 += 2.f * bh(vi);
        float di = dinv[i];
        float2 bv = ((const float2*)bias)[zoff + c4];
        float h0 = fast_tanh(fmaf(di, a0, bv.x));
        float h1 = fast_tanh(fmaf(di, a1, bv.y));
        out[((size_t)i << 6) + zoff + c4] = (uint32)f2b(h0) | ((uint32)f2b(h1) << 16);
    }
}

extern "C" void kernel_launch(void* const* d_in, const int* in_sizes, int n_in,
                              void* d_out, int out_size, void* d_ws, size_t ws_size,
                              hipStream_t stream) {
    const float* x   = (const float*)d_in[0];
    const int* eidx  = (const int*)d_in[1];
    const float* W1  = (const float*)d_in[2];
    const float* b1  = (const float*)d_in[3];
    const float* W2  = (const float*)d_in[4];
    const float* b2  = (const float*)d_in[5];
    const float* lw1 = (const float*)d_in[6];
    const float* lb1 = (const float*)d_in[7];
    const float* lw2 = (const float*)d_in[8];
    const float* lb2 = (const float*)d_in[9];
    const float* lw3 = (const float*)d_in[10];
    const float* lb3 = (const float*)d_in[11];
    const float* lw4 = (const float*)d_in[12];
    const float* lb4 = (const float*)d_in[13];
    float* out = (float*)d_out;

    const int N = in_sizes[0] / 128;
    const int E = in_sizes[1] / 2;

    // workspace carve (256B aligned)
    char* p = (char*)d_ws;
    auto alloc = [&](size_t bytes) -> void* {
        void* q = (void*)p;
        p += (bytes + 255) & ~(size_t)255;
        return q;
    };
    float* dinv      = (float*)alloc((size_t)N * 4);
    int* rowp        = (int*)alloc((size_t)(N + 1) * 4);
    uint32* bkt_size = (uint32*)alloc(MAXBK * 4);
    uint32* bkt_base = (uint32*)alloc(MAXBK * 4);
    uint32* bkt_cur  = (uint32*)alloc(MAXBK * 4);
    int* csr         = (int*)alloc((size_t)E * 4);
    unsigned short* Wt_hi = (unsigned short*)alloc(5 * 16384 * 2);
    unsigned short* Wt_lo = (unsigned short*)alloc(5 * 16384 * 2);
    unsigned short* bufA  = (unsigned short*)alloc((size_t)(N + 1) * 128 * 2);
    unsigned short* bufB  = (unsigned short*)alloc((size_t)(N + 1) * 128 * 2);
    uint32* packed = (uint32*)bufA;  // alias: bytes [0, 4E) dead before gemm1 writes bufA

    const int MB4 = (N + 127) / 128;
    const int AB  = (N + 3) / 4;
    const int NCH = (E + CHUNK - 1) / CHUNK;
    const int NBK = (N + 255) >> 8;  // must be <= MAXBK

    // zero-row for agg padding (row N); packed alias covers < 4E = 12.8MB, row N at 25.6MB
    hipMemsetAsync(bufA + (size_t)N * 128, 0, 256, stream);
    hipMemsetAsync(bkt_size, 0, MAXBK * 4, stream);
    countb_k<<<NCH, 256, 0, stream>>>(eidx, bkt_size, E);
    prep_w6_k<<<320, 256, 0, stream>>>(W1, W2, lw1, lw2, lw3, Wt_hi, Wt_lo);
    scanb_k<<<1, MAXBK, 0, stream>>>(bkt_size, bkt_base, bkt_cur, NBK);
    scatterb_k<<<NCH, 256, 0, stream>>>(eidx, bkt_cur, packed, E);
    buildb_k<<<NBK, 256, 0, stream>>>(packed, bkt_base, bkt_size, rowp, dinv, csr, N, E);

    const unsigned short* WH = Wt_hi;
    const unsigned short* WL = Wt_lo;

    // conv1: z1 = dinv*(x@W1) in bufA; h1 = tanh(dinv*(sum+2self)+b1) in bufB (2 passes)
    gemm_z_k<0><<<MB4, 256, 0, stream>>>(x, WH + 0 * 16384, WL + 0 * 16384, dinv, bufA, N);
    agg_half_k<<<AB, 256, 0, stream>>>((const uint32*)bufA, rowp, csr, dinv, b1,
                                       (uint32*)bufB, N, 0);
    agg_half_k<<<AB, 256, 0, stream>>>((const uint32*)bufA, rowp, csr, dinv, b1,
                                       (uint32*)bufB, N, 32);
    // conv2
    gemm_z_k<1><<<MB4, 256, 0, stream>>>(bufB, WH + 1 * 16384, WL + 1 * 16384, dinv, bufA, N);
    agg_half_k<<<AB, 256, 0, stream>>>((const uint32*)bufA, rowp, csr, dinv, b2,
                                       (uint32*)bufB, N, 0);
    agg_half_k<<<AB, 256, 0, stream>>>((const uint32*)bufA, rowp, csr, dinv, b2,
                                       (uint32*)bufB, N, 32);
    // fused MLP head (lw1..lw3 + lw4)
    mlp_fused_k<<<MB4, 256, 0, stream>>>(bufB, WH + 2 * 16384, WL + 2 * 16384,
                                         lb1, lb2, lb3, lw4, lb4, out, N);
}